// Round 10
// baseline (184.304 us; speedup 1.0000x reference)
//
#include <hip/hip_runtime.h>
#include <hip/hip_bf16.h>
#include <cstdint>
#include <cstddef>

// ---------------------------------------------------------------------------
// GraphSAGE 2-layer forward (mean aggregator), MI355X / gfx950.
//
//   h  = relu(x @ Ws1.T + mean_nbr1(x) @ Wn1.T + b1)
//   out = h @ Ws2.T + mean_nbr2(h) @ Wn2.T + b2
//
// Structure (round 10):
//   k_prep (merged): xcat[:,0:128]=bf16(x); w1f/w2f frag-major bf16;
//                    per-chunk LDS bucket histograms (dst>>8)
//   scan/scat/bcsr:  atomic-free two-level counting sort -> CSR
//   k_agg1:          xcat[:,128:256] = bf16(mean1(x))      (CSR gather)
//   k_gemm1:         BARRIER-FREE, LDS-FREE. 64rx256c block (4 waves x 64c).
//                    x-frags per-lane from global (L3/L2), w1 frag-major (L2),
//                    acc[4][4] swap-layout -> h global bf16 (bf16x4 stores).
//   k_gemm2:         BARRIER-FREE, LDS-FREE. 128r block (4 waves x 32r).
//                    h k-slices are per-lane contiguous -> direct global frags.
//                    out f32 + b2; p bf16.
//   k_agg2fin:       out += mean2(p)   (bf16 gather)
//
// Round-1: fp32-atomic scatter = atomic-bound (1009us) -> CSR gather.
// Round-2: f32 A-frags from global + strided B = latency-bound GEMM (5% mfma).
// Round-3: global-atomic CSR fill = 84MB HBM RMW for 4.8MB -> LDS sort.
// Round-4: redundant per-wave global A-loads -> LDS-staged A (68->47us).
// Round-5..9: fused kernel INVARIANT ~46us across occupancy/VGPR/tile/weight
//   -traffic configs; MfmaUtil 13% => 80% wait. Cause: 3 block-wide barriers
//   + 8 waves/CU (LDS cap) -> no TLP to hide L2/LDS chains. Fix: split into
//   two barrier-free LDS-free GEMMs (h round-trip via L3), 16 waves/CU.
// ---------------------------------------------------------------------------

#define D_IN 128
#define D_H  256
#define D_C  40

#define NBLK     128      // chunks per layer for hist/scatter
#define NBKT_MAX 392      // max coarse buckets (ceil(100000/256)=391)
#define BKT_CAP  2560     // max edges per bucket staged in LDS (mean 1536)

typedef __bf16 bf16_t;
typedef __attribute__((ext_vector_type(8))) __bf16 bf16x8;
typedef __attribute__((ext_vector_type(4))) __bf16 bf16x4;
typedef __attribute__((ext_vector_type(4))) float  f32x4;

// ---------------- ws layout (bytes), 256B-aligned ----------------
static constexpr size_t NMAX = 100000;
static constexpr size_t EMAX = 600000;
static constexpr size_t NSC_MAX = (size_t)NBKT_MAX * NBLK;
static constexpr size_t alignup(size_t v) { return (v + 255) & ~size_t(255); }

static constexpr size_t HG1_OFF  = 0;                                   // int[NSC]
static constexpr size_t HG2_OFF  = alignup(HG1_OFF + NSC_MAX * 4);      // int[NSC]
static constexpr size_t BS1_OFF  = alignup(HG2_OFF + NSC_MAX * 4);      // int[512]
static constexpr size_t BS2_OFF  = alignup(BS1_OFF + 512 * 4);
static constexpr size_t RP1_OFF  = alignup(BS2_OFF + 512 * 4);          // int[N+1]
static constexpr size_t RP2_OFF  = alignup(RP1_OFF + (NMAX + 1) * 4);
static constexpr size_t BKT1_OFF = alignup(RP2_OFF + (NMAX + 1) * 4);   // u32[E] (later csr1)
static constexpr size_t BKT2_OFF = alignup(BKT1_OFF + EMAX * 4);        // u32[E] (later csr2)
static constexpr size_t XCAT_OFF = alignup(BKT2_OFF + EMAX * 4);        // bf16[N+128][256]
static constexpr size_t HB_OFF   = alignup(XCAT_OFF + (NMAX + 128) * 256 * 2); // bf16[N+128][256]
static constexpr size_t P_OFF    = alignup(HB_OFF + (NMAX + 128) * 256 * 2);   // bf16[N][40]
static constexpr size_t W1F_OFF  = alignup(P_OFF + NMAX * 40 * 2);      // bf16 32*256*8
static constexpr size_t W2F_OFF  = alignup(W1F_OFF + 32 * 256 * 8 * 2); // bf16 32*80*8
static constexpr size_t WS_NEEDED = W2F_OFF + 32 * 80 * 8 * 2;

// ---------------- merged prep: convx + conv_w + hist ----------------
__global__ __launch_bounds__(256) void k_prep(
    const float* __restrict__ x, bf16_t* __restrict__ xcat,
    const float* __restrict__ ws1, const float* __restrict__ wn1,
    const float* __restrict__ ws2, const float* __restrict__ wn2,
    bf16_t* __restrict__ w1f, bf16_t* __restrict__ w2f,
    const int* __restrict__ dst1, const int* __restrict__ dst2,
    int* __restrict__ hg1, int* __restrict__ hg2,
    int N, int E, int chunk, int nbkt, int nconvx) {
  __shared__ int h[NBKT_MAX];
  int bid = blockIdx.x;

  if (bid < nconvx) {                       // ---- x -> bf16 into xcat[:,0:128]
    int t = bid * 256 + threadIdx.x;
    if (t < N * 16) {
      int row = t >> 4, j = t & 15;
      const float* sp = x + (size_t)row * 128 + j * 8;
      float4 v0 = ((const float4*)sp)[0];
      float4 v1 = ((const float4*)sp)[1];
      bf16x8 o;
      o[0] = (bf16_t)v0.x; o[1] = (bf16_t)v0.y; o[2] = (bf16_t)v0.z; o[3] = (bf16_t)v0.w;
      o[4] = (bf16_t)v1.x; o[5] = (bf16_t)v1.y; o[6] = (bf16_t)v1.z; o[7] = (bf16_t)v1.w;
      *(bf16x8*)(xcat + (size_t)row * 256 + j * 8) = o;
    }
    return;
  }
  bid -= nconvx;

  if (bid < 32) {                           // ---- weights -> bf16 frag-major
    int t = bid * 256 + threadIdx.x;
    {
      int ks4g = t >> 8, col = t & 255;
      int k0 = (ks4g >> 2) * 32 + (ks4g & 3) * 8;
      bf16x8 o;
#pragma unroll
      for (int i = 0; i < 8; ++i) {
        int k = k0 + i;   // K-concat: k<128 -> Ws1, else Wn1
        float v = (k < 128) ? ws1[col * 128 + k] : wn1[col * 128 + (k - 128)];
        o[i] = (bf16_t)v;
      }
      *(bf16x8*)(w1f + (size_t)t * 8) = o;
    }
    if (t < 32 * 80) {
      int ks4g = t / 80, col = t - ks4g * 80;
      int k0 = (ks4g >> 2) * 32 + (ks4g & 3) * 8;
      bf16x8 o;
#pragma unroll
      for (int i = 0; i < 8; ++i) {
        int k = k0 + i;   // col-concat: col<40 -> Ws2, else Wn2
        float v = (col < 40) ? ws2[col * 256 + k] : wn2[(col - 40) * 256 + k];
        o[i] = (bf16_t)v;
      }
      *(bf16x8*)(w2f + (size_t)t * 8) = o;
    }
    return;
  }
  bid -= 32;                                 // ---- histogram: bid in [0, 256)
  {
    const int* dst = (bid >> 7) ? dst2 : dst1;
    int*       hg  = (bid >> 7) ? hg2 : hg1;
    int        cb  = bid & 127;
    for (int i = threadIdx.x; i < nbkt; i += 256) h[i] = 0;
    __syncthreads();
    int beg = cb * chunk, end = min(E, beg + chunk);
    for (int e = beg + threadIdx.x; e < end; e += 256)
      atomicAdd(&h[dst[e] >> 8], 1);
    __syncthreads();
    for (int b = threadIdx.x; b < nbkt; b += 256)
      hg[b * NBLK + cb] = h[b];   // bucket-major, chunk-minor
  }
}

// ---------------- hierarchical exclusive scan (in-place) ----------------
__global__ void k_scan_block(int* __restrict__ a1, int* __restrict__ a2,
                             int* __restrict__ b1s, int* __restrict__ b2s, int n) {
  int* a    = blockIdx.y ? a2 : a1;
  int* bsum = blockIdx.y ? b2s : b1s;
  __shared__ int lds[256];
  int t = threadIdx.x, i = blockIdx.x * 256 + t;
  int v = (i < n) ? a[i] : 0;
  lds[t] = v;
  __syncthreads();
  for (int off = 1; off < 256; off <<= 1) {
    int add = (t >= off) ? lds[t - off] : 0;
    __syncthreads();
    lds[t] += add;
    __syncthreads();
  }
  if (i < n) a[i] = lds[t] - v;
  if (t == 255) bsum[blockIdx.x] = lds[255];
}

__global__ void k_scan_sums(int* __restrict__ b1s, int* __restrict__ b2s, int nb) {
  int* bsum = blockIdx.x ? b2s : b1s;
  __shared__ int lds[512];
  int t = threadIdx.x;
  int v = (t < nb) ? bsum[t] : 0;
  lds[t] = v;
  __syncthreads();
  for (int off = 1; off < 512; off <<= 1) {
    int add = (t >= off) ? lds[t - off] : 0;
    __syncthreads();
    lds[t] += add;
    __syncthreads();
  }
  if (t < nb) bsum[t] = lds[t] - v;
}

__global__ void k_scan_add(int* __restrict__ a1, int* __restrict__ a2,
                           const int* __restrict__ b1s, const int* __restrict__ b2s, int n) {
  int* a        = blockIdx.y ? a2 : a1;
  const int* bs = blockIdx.y ? b2s : b1s;
  int i = blockIdx.x * 256 + threadIdx.x;
  if (i < n) a[i] += bs[i >> 8];
}

// ---------------- scatter into bucketed array (LDS cursors) ----------------
__global__ void k_scat(const int* __restrict__ src1, const int* __restrict__ dst1,
                       const int* __restrict__ src2, const int* __restrict__ dst2,
                       const int* __restrict__ off1, const int* __restrict__ off2,
                       unsigned* __restrict__ bkt1, unsigned* __restrict__ bkt2,
                       int E, int chunk, int nbkt) {
  const int* src = blockIdx.y ? src2 : src1;
  const int* dst = blockIdx.y ? dst2 : dst1;
  const int* off = blockIdx.y ? off2 : off1;
  unsigned*  bkt = blockIdx.y ? bkt2 : bkt1;
  __shared__ int cur[NBKT_MAX];
  for (int i = threadIdx.x; i < nbkt; i += 256)
    cur[i] = off[i * NBLK + blockIdx.x];
  __syncthreads();
  int beg = blockIdx.x * chunk, end = min(E, beg + chunk);
  for (int e = beg + threadIdx.x; e < end; e += 256) {
    int d = dst[e];
    int slot = atomicAdd(&cur[d >> 8], 1);
    bkt[slot] = (unsigned)src[e] | ((unsigned)(d & 255) << 24);
  }
}

// ---------------- per-bucket LDS counting sort -> CSR + rowptr ----------------
__global__ __launch_bounds__(256) void k_bcsr(
    const int* __restrict__ off1, const int* __restrict__ off2,
    const unsigned* bkt1, const unsigned* bkt2,
    int* csr1, int* csr2,
    int* __restrict__ rp1, int* __restrict__ rp2, int E, int N, int nbkt) {
  const int* off      = blockIdx.y ? off2 : off1;
  const unsigned* bkt = blockIdx.y ? bkt2 : bkt1;
  int* csr            = blockIdx.y ? csr2 : csr1;
  int* rowptr         = blockIdx.y ? rp2 : rp1;

  const int b = blockIdx.x, t = threadIdx.x;
  const int base = off[b * NBLK];
  const int endp = (b == nbkt - 1) ? E : off[(b + 1) * NBLK];
  const int cnt  = endp - base;

  __shared__ int hist[256];
  __shared__ int sc[256];
  __shared__ int cur[256];
  __shared__ int stage[BKT_CAP];

  hist[t] = 0;
  __syncthreads();
  for (int i = t; i < cnt; i += 256)
    atomicAdd(&hist[bkt[base + i] >> 24], 1);
  __syncthreads();

  int v = hist[t];
  sc[t] = v;
  __syncthreads();
  for (int off_ = 1; off_ < 256; off_ <<= 1) {
    int add = (t >= off_) ? sc[t - off_] : 0;
    __syncthreads();
    sc[t] += add;
    __syncthreads();
  }
  int excl = sc[t] - v;

  int node = b * 256 + t;
  if (node < N) rowptr[node] = base + excl;
  if (b == nbkt - 1 && t == 0) rowptr[N] = E;
  cur[t] = excl;
  __syncthreads();

  for (int i = t; i < cnt; i += 256) {
    unsigned u = bkt[base + i];
    int slot = atomicAdd(&cur[u >> 24], 1);
    if (slot < BKT_CAP) stage[slot] = (int)(u & 0xFFFFFFu);
  }
  __syncthreads();
  for (int i = t; i < cnt; i += 256)
    csr[base + i] = stage[i];
}

// ---------------- layer-1 mean -> xcat[:,128:256] (bf16 gather) ----------------
__global__ void k_agg1(bf16_t* __restrict__ xcat, const int* __restrict__ rowptr,
                       const int* __restrict__ csr, int N) {
  int t = blockIdx.x * 256 + threadIdx.x;
  int node = t >> 4, l = t & 15;
  if (node >= N) return;
  int beg = rowptr[node], end = rowptr[node + 1];
  float acc[8] = {0.f, 0.f, 0.f, 0.f, 0.f, 0.f, 0.f, 0.f};
  for (int e = beg; e < end; ++e) {
    int s = csr[e];
    bf16x8 v = *(const bf16x8*)(xcat + (size_t)s * 256 + l * 8);
#pragma unroll
    for (int i = 0; i < 8; ++i) acc[i] += (float)v[i];
  }
  float rd = (end > beg) ? 1.0f / (float)(end - beg) : 0.0f;
  bf16x8 o;
#pragma unroll
  for (int i = 0; i < 8; ++i) o[i] = (bf16_t)(acc[i] * rd);
  *(bf16x8*)(xcat + (size_t)node * 256 + 128 + l * 8) = o;
}

// ---------------- GEMM1: h = relu(xcat @ w1.T + b1), barrier/LDS-free --------
// Block 64 rows x 256 cols, 4 waves (wave = 64 cols). Fully independent waves:
// x-frags per-lane 16B from global (L3/L2-resident xcat; 4x cross-wave
// redundancy is absorbed by L2), w1 frag-major (L2). acc[wb][rb] swap layout:
// lane = (row lr, 4 consecutive cols) -> packed bf16x4 h-stores.
__global__ __launch_bounds__(256, 4) void k_gemm1(
    const bf16_t* __restrict__ xcat, const bf16_t* __restrict__ w1f,
    const float* __restrict__ b1, bf16_t* __restrict__ hb, int N) {
  const int tid  = (int)threadIdx.x;
  const int wv   = tid >> 6;
  const int lane = tid & 63;
  const int lr   = lane & 15;
  const int lg   = lane >> 4;
  const int c0   = wv * 64;
  const int m0   = (int)blockIdx.x * 64;

  // per-rb row base pointers (k-offset folds into imm offsets)
  const bf16_t* xrow[4];
#pragma unroll
  for (int rb = 0; rb < 4; ++rb)
    xrow[rb] = xcat + (size_t)(m0 + rb * 16 + lr) * 256 + lg * 8;

  f32x4 acc[4][4] = {};
#pragma unroll
  for (int ks = 0; ks < 8; ++ks) {
    bf16x8 wf[4];
#pragma unroll
    for (int wb = 0; wb < 4; ++wb)
      wf[wb] = *(const bf16x8*)(w1f + ((size_t)(ks * 4 + lg) * 256 +
                                       (c0 + wb * 16 + lr)) * 8);
    bf16x8 ax[4];
#pragma unroll
    for (int rb = 0; rb < 4; ++rb)
      ax[rb] = *(const bf16x8*)(xrow[rb] + ks * 32);
#pragma unroll
    for (int wb = 0; wb < 4; ++wb)
#pragma unroll
      for (int rb = 0; rb < 4; ++rb)
        acc[wb][rb] = __builtin_amdgcn_mfma_f32_16x16x32_bf16(
            wf[wb], ax[rb], acc[wb][rb], 0, 0, 0);
  }

  // epilogue: D layout lane&15 = x-row, (lane>>4)*4+i = w-col.
#pragma unroll
  for (int wb = 0; wb < 4; ++wb) {
    float4 b4 = *(const float4*)(b1 + c0 + wb * 16 + lg * 4);
#pragma unroll
    for (int rb = 0; rb < 4; ++rb) {
      int r = m0 + rb * 16 + lr;
      if (r < N) {
        bf16x4 o;
        o[0] = (bf16_t)fmaxf(acc[wb][rb][0] + b4.x, 0.f);
        o[1] = (bf16_t)fmaxf(acc[wb][rb][1] + b4.y, 0.f);
        o[2] = (bf16_t)fmaxf(acc[wb][rb][2] + b4.z, 0.f);
        o[3] = (bf16_t)fmaxf(acc[wb][rb][3] + b4.w, 0.f);
        *(bf16x4*)(hb + (size_t)r * 256 + c0 + wb * 16 + lg * 4) = o;
      }
    }
  }
}

// ---------------- GEMM2: [out|p] = h @ w2.T, barrier/LDS-free ----------------
// Block 128 rows, 4 waves x 32 rows. h k-slices are per-lane CONTIGUOUS in
// row-major h -> direct 16B global frags (L3-resident). acc2[m][wb].
__global__ __launch_bounds__(256, 4) void k_gemm2(
    const bf16_t* __restrict__ hb, const bf16_t* __restrict__ w2f,
    const float* __restrict__ b2v, float* __restrict__ out,
    bf16_t* __restrict__ p, int N) {
  const int tid  = (int)threadIdx.x;
  const int wv   = tid >> 6;
  const int lane = tid & 63;
  const int lr   = lane & 15;
  const int lg   = lane >> 4;
  const int r0   = (int)blockIdx.x * 128 + wv * 32;

  const bf16_t* hrow[2];
#pragma unroll
  for (int m = 0; m < 2; ++m)
    hrow[m] = hb + (size_t)(r0 + m * 16 + lr) * 256 + lg * 8;

  f32x4 acc2[2][5] = {};
#pragma unroll
  for (int ks = 0; ks < 8; ++ks) {
    bf16x8 hf[2];
#pragma unroll
    for (int m = 0; m < 2; ++m)
      hf[m] = *(const bf16x8*)(hrow[m] + ks * 32);
#pragma unroll
    for (int wb = 0; wb < 5; ++wb) {
      bf16x8 w2 = *(const bf16x8*)(w2f + ((size_t)(ks * 4 + lg) * 80 +
                                          (wb * 16 + lr)) * 8);
#pragma unroll
      for (int m = 0; m < 2; ++m)
        acc2[m][wb] = __builtin_amdgcn_mfma_f32_16x16x32_bf16(
            w2, hf[m], acc2[m][wb], 0, 0, 0);
    }
  }

#pragma unroll
  for (int m = 0; m < 2; ++m) {
    const int r = r0 + m * 16 + lr;
    if (r < N) {
#pragma unroll
      for (int wb = 0; wb < 5; ++wb) {
        int col0 = wb * 16 + lg * 4;
        f32x4 v = acc2[m][wb];
        if (col0 < 40) {
          float4 b4 = *(const float4*)(b2v + col0);
          v[0] += b4.x; v[1] += b4.y; v[2] += b4.z; v[3] += b4.w;
          *(f32x4*)(out + (size_t)r * 40 + col0) = v;
        } else {
          bf16x4 o;
          o[0] = (bf16_t)v[0]; o[1] = (bf16_t)v[1];
          o[2] = (bf16_t)v[2]; o[3] = (bf16_t)v[3];
          *(bf16x4*)(p + (size_t)r * 40 + (col0 - 40)) = o;
        }
      }
    }
  }
}

// ---------------- layer-2 mean fused epilogue: out += mean2(p), bf16 gather ----
__global__ void k_agg2fin(const bf16_t* __restrict__ p, const int* __restrict__ rowptr,
                          const int* __restrict__ csr, float* __restrict__ out, int N) {
  int t = blockIdx.x * 256 + threadIdx.x;
  int node = t / 10, l = t - node * 10;
  if (node >= N) return;
  int beg = rowptr[node], end = rowptr[node + 1];
  float a0 = 0.f, a1 = 0.f, a2 = 0.f, a3 = 0.f;
  for (int e = beg; e < end; ++e) {
    int s = csr[e];
    bf16x4 v = *(const bf16x4*)(p + (size_t)s * 40 + l * 4);
    a0 += (float)v[0]; a1 += (float)v[1]; a2 += (float)v[2]; a3 += (float)v[3];
  }
  float rd = (end > beg) ? 1.0f / (float)(end - beg) : 0.0f;
  float* o = out + (size_t)node * 40 + l * 4;
  float4 cur = *(const float4*)o;
  cur.x += a0 * rd;
  cur.y += a1 * rd;
  cur.z += a2 * rd;
  cur.w += a3 * rd;
  *(float4*)o = cur;
}

extern "C" void kernel_launch(void* const* d_in, const int* in_sizes, int n_in,
                              void* d_out, int out_size, void* d_ws, size_t ws_size,
                              hipStream_t stream) {
  const float* x    = (const float*)d_in[0];
  const int*   src1 = (const int*)d_in[1];
  const int*   dst1 = (const int*)d_in[2];
  const int*   src2 = (const int*)d_in[3];
  const int*   dst2 = (const int*)d_in[4];
  const float* ws1  = (const float*)d_in[5];
  const float* wn1  = (const float*)d_in[6];
  const float* b1   = (const float*)d_in[7];
  const float* ws2  = (const float*)d_in[8];
  const float* wn2  = (const float*)d_in[9];
  const float* b2   = (const float*)d_in[10];
  float*       out  = (float*)d_out;

  const int N = in_sizes[0] / D_IN;
  const int E = in_sizes[1];
  if (ws_size < WS_NEEDED) return;

  char*     ws   = (char*)d_ws;
  int*      hg1  = (int*)(ws + HG1_OFF);
  int*      hg2  = (int*)(ws + HG2_OFF);
  int*      bs1  = (int*)(ws + BS1_OFF);
  int*      bs2  = (int*)(ws + BS2_OFF);
  int*      rp1  = (int*)(ws + RP1_OFF);
  int*      rp2  = (int*)(ws + RP2_OFF);
  unsigned* bkt1 = (unsigned*)(ws + BKT1_OFF);
  unsigned* bkt2 = (unsigned*)(ws + BKT2_OFF);
  int*      csr1 = (int*)(ws + BKT1_OFF);     // aliases bkt1 (safe: see k_bcsr)
  int*      csr2 = (int*)(ws + BKT2_OFF);     // aliases bkt2
  bf16_t*   xcat = (bf16_t*)(ws + XCAT_OFF);
  bf16_t*   hbuf = (bf16_t*)(ws + HB_OFF);
  bf16_t*   p    = (bf16_t*)(ws + P_OFF);
  bf16_t*   w1f  = (bf16_t*)(ws + W1F_OFF);
  bf16_t*   w2f  = (bf16_t*)(ws + W2F_OFF);

  const int nbkt  = (N + 255) >> 8;            // 391
  const int chunk = (E + NBLK - 1) / NBLK;     // 4688
  const int nsc   = nbkt * NBLK;               // 50048
  const int nscb  = (nsc + 255) / 256;         // 196 (<=512)
  const int nconvx = (N * 16 + 255) / 256;     // 6250

  k_prep<<<nconvx + 32 + 2 * NBLK, 256, 0, stream>>>(
      x, xcat, ws1, wn1, ws2, wn2, w1f, w2f, dst1, dst2, hg1, hg2,
      N, E, chunk, nbkt, nconvx);

  k_scan_block<<<dim3(nscb, 2), 256, 0, stream>>>(hg1, hg2, bs1, bs2, nsc);
  k_scan_sums<<<2, 512, 0, stream>>>(bs1, bs2, nscb);
  k_scan_add<<<dim3(nscb, 2), 256, 0, stream>>>(hg1, hg2, bs1, bs2, nsc);
  k_scat<<<dim3(NBLK, 2), 256, 0, stream>>>(src1, dst1, src2, dst2, hg1, hg2,
                                            bkt1, bkt2, E, chunk, nbkt);
  k_bcsr<<<dim3(nbkt, 2), 256, 0, stream>>>(hg1, hg2, bkt1, bkt2, csr1, csr2,
                                            rp1, rp2, E, N, nbkt);

  k_agg1<<<(N * 16 + 255) / 256, 256, 0, stream>>>(xcat, rp1, csr1, N);
  k_gemm1<<<(N + 63) / 64, 256, 0, stream>>>(xcat, w1f, b1, hbuf, N);
  k_gemm2<<<(N + 127) / 128, 256, 0, stream>>>(hbuf, w2f, b2, out, p, N);
  k_agg2fin<<<(N * 10 + 255) / 256, 256, 0, stream>>>(p, rp2, csr2, out, N);
}

// Round 11
// 174.526 us; speedup vs baseline: 1.0560x; 1.0560x over previous
//
#include <hip/hip_runtime.h>
#include <hip/hip_bf16.h>
#include <cstdint>
#include <cstddef>

// ---------------------------------------------------------------------------
// GraphSAGE 2-layer forward (mean aggregator), MI355X / gfx950.
//
//   h  = relu(x @ Ws1.T + mean_nbr1(x) @ Wn1.T + b1)
//   out = h @ Ws2.T + mean_nbr2(h) @ Wn2.T + b2
//
// Structure (round 11):
//   k_prep / sort / k_agg1 / k_agg2fin: unchanged from round 9.
//   k_fused: ZERO-BARRIER wave-private design. Each wave owns 32 rows:
//     phase A: acc[16][2] (128 VGPR) = full 256-col h for 32 rows;
//              per-ks: 2 x-frag loads (per-lane, line-coalesced) +
//              16 w1-frag loads (L2, 16-deep MLP). x read ONCE (no
//              cross-wave redundancy). W1 loaded once per 32 rows.
//     h hand-off: wave-private 16KB LDS slab (layout shuffle only);
//              cross-lane visibility = lgkmcnt(0) + sched_barrier(0).
//              NO s_barrier anywhere in the kernel.
//     phase B: acc2[2][5] = mfma(w2, h_lds) -> out f32x4 / p bf16x4.
//
// Round-1: fp32-atomic scatter = atomic-bound -> CSR gather.
// Round-3: global-atomic CSR fill = HBM RMW -> LDS counting sort.
// Round-5..9: block-wide-barrier fused kernel INVARIANT ~46us across
//   occupancy/VGPR/tile/weight-traffic configs; 75% dead time = barrier
//   convoys x 2 blocks/CU. Round-10: split GEMMs regress (h round-trip,
//   2x write amplification on the 51MB h buffer). Fix: fuse WITHOUT
//   block-wide sync — wave-private h, zero barriers, free-running waves.
// ---------------------------------------------------------------------------

#define D_IN 128
#define D_H  256
#define D_C  40

#define NBLK     128
#define NBKT_MAX 392
#define BKT_CAP  2560

typedef __bf16 bf16_t;
typedef __attribute__((ext_vector_type(8))) __bf16 bf16x8;
typedef __attribute__((ext_vector_type(4))) __bf16 bf16x4;
typedef __attribute__((ext_vector_type(4))) float  f32x4;

// ---------------- ws layout (bytes), 256B-aligned ----------------
static constexpr size_t NMAX = 100000;
static constexpr size_t EMAX = 600000;
static constexpr size_t NSC_MAX = (size_t)NBKT_MAX * NBLK;
static constexpr size_t alignup(size_t v) { return (v + 255) & ~size_t(255); }

static constexpr size_t HG1_OFF  = 0;
static constexpr size_t HG2_OFF  = alignup(HG1_OFF + NSC_MAX * 4);
static constexpr size_t BS1_OFF  = alignup(HG2_OFF + NSC_MAX * 4);
static constexpr size_t BS2_OFF  = alignup(BS1_OFF + 512 * 4);
static constexpr size_t RP1_OFF  = alignup(BS2_OFF + 512 * 4);
static constexpr size_t RP2_OFF  = alignup(RP1_OFF + (NMAX + 1) * 4);
static constexpr size_t BKT1_OFF = alignup(RP2_OFF + (NMAX + 1) * 4);
static constexpr size_t BKT2_OFF = alignup(BKT1_OFF + EMAX * 4);
static constexpr size_t XCAT_OFF = alignup(BKT2_OFF + EMAX * 4);        // bf16[N+128][256]
static constexpr size_t P_OFF    = alignup(XCAT_OFF + (NMAX + 128) * 256 * 2); // bf16[N][40]
static constexpr size_t W1F_OFF  = alignup(P_OFF + NMAX * 40 * 2);
static constexpr size_t W2F_OFF  = alignup(W1F_OFF + 32 * 256 * 8 * 2);
static constexpr size_t WS_NEEDED = W2F_OFF + 32 * 80 * 8 * 2;

// ---------------- merged prep: convx + conv_w + hist ----------------
__global__ __launch_bounds__(256) void k_prep(
    const float* __restrict__ x, bf16_t* __restrict__ xcat,
    const float* __restrict__ ws1, const float* __restrict__ wn1,
    const float* __restrict__ ws2, const float* __restrict__ wn2,
    bf16_t* __restrict__ w1f, bf16_t* __restrict__ w2f,
    const int* __restrict__ dst1, const int* __restrict__ dst2,
    int* __restrict__ hg1, int* __restrict__ hg2,
    int N, int E, int chunk, int nbkt, int nconvx) {
  __shared__ int h[NBKT_MAX];
  int bid = blockIdx.x;

  if (bid < nconvx) {
    int t = bid * 256 + threadIdx.x;
    if (t < N * 16) {
      int row = t >> 4, j = t & 15;
      const float* sp = x + (size_t)row * 128 + j * 8;
      float4 v0 = ((const float4*)sp)[0];
      float4 v1 = ((const float4*)sp)[1];
      bf16x8 o;
      o[0] = (bf16_t)v0.x; o[1] = (bf16_t)v0.y; o[2] = (bf16_t)v0.z; o[3] = (bf16_t)v0.w;
      o[4] = (bf16_t)v1.x; o[5] = (bf16_t)v1.y; o[6] = (bf16_t)v1.z; o[7] = (bf16_t)v1.w;
      *(bf16x8*)(xcat + (size_t)row * 256 + j * 8) = o;
    }
    return;
  }
  bid -= nconvx;

  if (bid < 32) {
    int t = bid * 256 + threadIdx.x;
    {
      int ks4g = t >> 8, col = t & 255;
      int k0 = (ks4g >> 2) * 32 + (ks4g & 3) * 8;
      bf16x8 o;
#pragma unroll
      for (int i = 0; i < 8; ++i) {
        int k = k0 + i;
        float v = (k < 128) ? ws1[col * 128 + k] : wn1[col * 128 + (k - 128)];
        o[i] = (bf16_t)v;
      }
      *(bf16x8*)(w1f + (size_t)t * 8) = o;
    }
    if (t < 32 * 80) {
      int ks4g = t / 80, col = t - ks4g * 80;
      int k0 = (ks4g >> 2) * 32 + (ks4g & 3) * 8;
      bf16x8 o;
#pragma unroll
      for (int i = 0; i < 8; ++i) {
        int k = k0 + i;
        float v = (col < 40) ? ws2[col * 256 + k] : wn2[(col - 40) * 256 + k];
        o[i] = (bf16_t)v;
      }
      *(bf16x8*)(w2f + (size_t)t * 8) = o;
    }
    return;
  }
  bid -= 32;
  {
    const int* dst = (bid >> 7) ? dst2 : dst1;
    int*       hg  = (bid >> 7) ? hg2 : hg1;
    int        cb  = bid & 127;
    for (int i = threadIdx.x; i < nbkt; i += 256) h[i] = 0;
    __syncthreads();
    int beg = cb * chunk, end = min(E, beg + chunk);
    for (int e = beg + threadIdx.x; e < end; e += 256)
      atomicAdd(&h[dst[e] >> 8], 1);
    __syncthreads();
    for (int b = threadIdx.x; b < nbkt; b += 256)
      hg[b * NBLK + cb] = h[b];
  }
}

// ---------------- hierarchical exclusive scan (in-place) ----------------
__global__ void k_scan_block(int* __restrict__ a1, int* __restrict__ a2,
                             int* __restrict__ b1s, int* __restrict__ b2s, int n) {
  int* a    = blockIdx.y ? a2 : a1;
  int* bsum = blockIdx.y ? b2s : b1s;
  __shared__ int lds[256];
  int t = threadIdx.x, i = blockIdx.x * 256 + t;
  int v = (i < n) ? a[i] : 0;
  lds[t] = v;
  __syncthreads();
  for (int off = 1; off < 256; off <<= 1) {
    int add = (t >= off) ? lds[t - off] : 0;
    __syncthreads();
    lds[t] += add;
    __syncthreads();
  }
  if (i < n) a[i] = lds[t] - v;
  if (t == 255) bsum[blockIdx.x] = lds[255];
}

__global__ void k_scan_sums(int* __restrict__ b1s, int* __restrict__ b2s, int nb) {
  int* bsum = blockIdx.x ? b2s : b1s;
  __shared__ int lds[512];
  int t = threadIdx.x;
  int v = (t < nb) ? bsum[t] : 0;
  lds[t] = v;
  __syncthreads();
  for (int off = 1; off < 512; off <<= 1) {
    int add = (t >= off) ? lds[t - off] : 0;
    __syncthreads();
    lds[t] += add;
    __syncthreads();
  }
  if (t < nb) bsum[t] = lds[t] - v;
}

__global__ void k_scan_add(int* __restrict__ a1, int* __restrict__ a2,
                           const int* __restrict__ b1s, const int* __restrict__ b2s, int n) {
  int* a        = blockIdx.y ? a2 : a1;
  const int* bs = blockIdx.y ? b2s : b1s;
  int i = blockIdx.x * 256 + threadIdx.x;
  if (i < n) a[i] += bs[i >> 8];
}

// ---------------- scatter into bucketed array (LDS cursors) ----------------
__global__ void k_scat(const int* __restrict__ src1, const int* __restrict__ dst1,
                       const int* __restrict__ src2, const int* __restrict__ dst2,
                       const int* __restrict__ off1, const int* __restrict__ off2,
                       unsigned* __restrict__ bkt1, unsigned* __restrict__ bkt2,
                       int E, int chunk, int nbkt) {
  const int* src = blockIdx.y ? src2 : src1;
  const int* dst = blockIdx.y ? dst2 : dst1;
  const int* off = blockIdx.y ? off2 : off1;
  unsigned*  bkt = blockIdx.y ? bkt2 : bkt1;
  __shared__ int cur[NBKT_MAX];
  for (int i = threadIdx.x; i < nbkt; i += 256)
    cur[i] = off[i * NBLK + blockIdx.x];
  __syncthreads();
  int beg = blockIdx.x * chunk, end = min(E, beg + chunk);
  for (int e = beg + threadIdx.x; e < end; e += 256) {
    int d = dst[e];
    int slot = atomicAdd(&cur[d >> 8], 1);
    bkt[slot] = (unsigned)src[e] | ((unsigned)(d & 255) << 24);
  }
}

// ---------------- per-bucket LDS counting sort -> CSR + rowptr ----------------
__global__ __launch_bounds__(256) void k_bcsr(
    const int* __restrict__ off1, const int* __restrict__ off2,
    const unsigned* bkt1, const unsigned* bkt2,
    int* csr1, int* csr2,
    int* __restrict__ rp1, int* __restrict__ rp2, int E, int N, int nbkt) {
  const int* off      = blockIdx.y ? off2 : off1;
  const unsigned* bkt = blockIdx.y ? bkt2 : bkt1;
  int* csr            = blockIdx.y ? csr2 : csr1;
  int* rowptr         = blockIdx.y ? rp2 : rp1;

  const int b = blockIdx.x, t = threadIdx.x;
  const int base = off[b * NBLK];
  const int endp = (b == nbkt - 1) ? E : off[(b + 1) * NBLK];
  const int cnt  = endp - base;

  __shared__ int hist[256];
  __shared__ int sc[256];
  __shared__ int cur[256];
  __shared__ int stage[BKT_CAP];

  hist[t] = 0;
  __syncthreads();
  for (int i = t; i < cnt; i += 256)
    atomicAdd(&hist[bkt[base + i] >> 24], 1);
  __syncthreads();

  int v = hist[t];
  sc[t] = v;
  __syncthreads();
  for (int off_ = 1; off_ < 256; off_ <<= 1) {
    int add = (t >= off_) ? sc[t - off_] : 0;
    __syncthreads();
    sc[t] += add;
    __syncthreads();
  }
  int excl = sc[t] - v;

  int node = b * 256 + t;
  if (node < N) rowptr[node] = base + excl;
  if (b == nbkt - 1 && t == 0) rowptr[N] = E;
  cur[t] = excl;
  __syncthreads();

  for (int i = t; i < cnt; i += 256) {
    unsigned u = bkt[base + i];
    int slot = atomicAdd(&cur[u >> 24], 1);
    if (slot < BKT_CAP) stage[slot] = (int)(u & 0xFFFFFFu);
  }
  __syncthreads();
  for (int i = t; i < cnt; i += 256)
    csr[base + i] = stage[i];
}

// ---------------- layer-1 mean -> xcat[:,128:256] (bf16 gather) ----------------
__global__ void k_agg1(bf16_t* __restrict__ xcat, const int* __restrict__ rowptr,
                       const int* __restrict__ csr, int N) {
  int t = blockIdx.x * 256 + threadIdx.x;
  int node = t >> 4, l = t & 15;
  if (node >= N) return;
  int beg = rowptr[node], end = rowptr[node + 1];
  float acc[8] = {0.f, 0.f, 0.f, 0.f, 0.f, 0.f, 0.f, 0.f};
  for (int e = beg; e < end; ++e) {
    int s = csr[e];
    bf16x8 v = *(const bf16x8*)(xcat + (size_t)s * 256 + l * 8);
#pragma unroll
    for (int i = 0; i < 8; ++i) acc[i] += (float)v[i];
  }
  float rd = (end > beg) ? 1.0f / (float)(end - beg) : 0.0f;
  bf16x8 o;
#pragma unroll
  for (int i = 0; i < 8; ++i) o[i] = (bf16_t)(acc[i] * rd);
  *(bf16x8*)(xcat + (size_t)node * 256 + 128 + l * 8) = o;
}

// ---------------- fused GEMM: zero-barrier, wave-private 32-row tiles --------
// 4 independent waves / block (no __syncthreads anywhere). Wave owns rows
// r0..r0+31. Phase A: acc[wb(16)][rb(2)] = full 256-col h in registers;
// per-ks: 2 x-frag loads (per-lane; 4 lg-lanes cover each 64B line) +
// 16 w1-frag loads (L2, coalesced, 16-deep MLP). x read exactly once.
// h hand-off via wave-private 16KB LDS slab (swizzle c ^= (row&7)<<4);
// cross-lane visibility enforced by lgkmcnt(0)+sched_barrier(0) (same-wave
// program order, no s_barrier needed). Phase B: acc2[2][5] = mfma(w2, h).
__global__ __launch_bounds__(256, 2) void k_fused(
    const bf16_t* __restrict__ xcat, const bf16_t* __restrict__ w1f,
    const float* __restrict__ b1, const bf16_t* __restrict__ w2f,
    const float* __restrict__ b2v, float* __restrict__ out,
    bf16_t* __restrict__ p, int N) {
  __shared__ __align__(16) char lds[65536];
  const int tid  = (int)threadIdx.x;
  const int wv   = tid >> 6;
  const int lane = tid & 63;
  const int lr   = lane & 15;
  const int lg   = lane >> 4;
  const int r0   = (int)blockIdx.x * 128 + wv * 32;
  char* hbuf = lds + wv * 16384;   // wave-private: 32 rows x 512B

  const bf16_t* xr0 = xcat + (size_t)(r0 + lr) * 256 + lg * 8;
  const bf16_t* xr1 = xr0 + 16 * 256;
  const bf16_t* wb0 = w1f + ((size_t)lg * 256 + lr) * 8;

  // ---- phase A: acc[wb][rb] = sum_ks mfma(w1[wb], x[rb]) ----
  f32x4 acc[16][2] = {};
#pragma unroll 1
  for (int ks = 0; ks < 8; ++ks) {
    bf16x8 ax0 = *(const bf16x8*)(xr0 + ks * 32);
    bf16x8 ax1 = *(const bf16x8*)(xr1 + ks * 32);
    const bf16_t* wk = wb0 + (size_t)ks * (4 * 256 * 8);
    bf16x8 wf[16];
#pragma unroll
    for (int wb = 0; wb < 16; ++wb)
      wf[wb] = *(const bf16x8*)(wk + wb * (16 * 8));
#pragma unroll
    for (int wb = 0; wb < 16; ++wb) {
      acc[wb][0] = __builtin_amdgcn_mfma_f32_16x16x32_bf16(wf[wb], ax0, acc[wb][0], 0, 0, 0);
      acc[wb][1] = __builtin_amdgcn_mfma_f32_16x16x32_bf16(wf[wb], ax1, acc[wb][1], 0, 0, 0);
    }
  }

  // ---- epilogue: h = relu(acc+b1) -> wave-private LDS (swizzled bf16x4) ----
  // D layout: lane&15 = x-row (within rb), (lane>>4)*4+i = w-col (within wb).
#pragma unroll
  for (int wb = 0; wb < 16; ++wb) {
    float4 b4 = *(const float4*)(b1 + wb * 16 + lg * 4);
#pragma unroll
    for (int rb = 0; rb < 2; ++rb) {
      int xrow = rb * 16 + lr;
      bf16x4 o;
      o[0] = (bf16_t)fmaxf(acc[wb][rb][0] + b4.x, 0.f);
      o[1] = (bf16_t)fmaxf(acc[wb][rb][1] + b4.y, 0.f);
      o[2] = (bf16_t)fmaxf(acc[wb][rb][2] + b4.z, 0.f);
      o[3] = (bf16_t)fmaxf(acc[wb][rb][3] + b4.w, 0.f);
      *(bf16x4*)(hbuf + xrow * 512 + ((wb * 32 + lg * 8) ^ ((xrow & 7) << 4))) = o;
    }
  }
  // cross-lane hand-off fence (same wave; no s_barrier): drain LDS writes,
  // and pin ordering so no ds_read is hoisted above the drain (guide §18).
  asm volatile("s_waitcnt lgkmcnt(0)" ::: "memory");
  __builtin_amdgcn_sched_barrier(0);

  // ---- phase B: acc2[m][wb] = sum_ks mfma(w2[wb], h[m]) ----
  f32x4 acc2[2][5] = {};
#pragma unroll 1
  for (int ks = 0; ks < 8; ++ks) {
    bf16x8 hf[2];
#pragma unroll
    for (int m = 0; m < 2; ++m) {
      int arow = m * 16 + lr;
      hf[m] = *(const bf16x8*)(hbuf + arow * 512 +
                               ((ks * 64 + lg * 16) ^ ((arow & 7) << 4)));
    }
#pragma unroll
    for (int wb = 0; wb < 5; ++wb) {
      bf16x8 w2 = *(const bf16x8*)(w2f + ((size_t)(ks * 4 + lg) * 80 +
                                          (wb * 16 + lr)) * 8);
#pragma unroll
      for (int m = 0; m < 2; ++m)
        acc2[m][wb] = __builtin_amdgcn_mfma_f32_16x16x32_bf16(
            w2, hf[m], acc2[m][wb], 0, 0, 0);
    }
  }

  // ---- stores: lane holds 4 consecutive out-cols for ONE row ----
#pragma unroll
  for (int m = 0; m < 2; ++m) {
    const int r = r0 + m * 16 + lr;
    if (r < N) {
#pragma unroll
      for (int wb = 0; wb < 5; ++wb) {
        int col0 = wb * 16 + lg * 4;
        f32x4 v = acc2[m][wb];
        if (col0 < 40) {
          float4 b4 = *(const float4*)(b2v + col0);
          v[0] += b4.x; v[1] += b4.y; v[2] += b4.z; v[3] += b4.w;
          *(f32x4*)(out + (size_t)r * 40 + col0) = v;
        } else {
          bf16x4 o;
          o[0] = (bf16_t)v[0]; o[1] = (bf16_t)v[1];
          o[2] = (bf16_t)v[2]; o[3] = (bf16_t)v[3];
          *(bf16x4*)(p + (size_t)r * 40 + (col0 - 40)) = o;
        }
      }
    }
  }
}

// ---------------- layer-2 mean fused epilogue: out += mean2(p), bf16 gather ----
__global__ void k_agg2fin(const bf16_t* __restrict__ p, const int* __restrict__ rowptr,
                          const int* __restrict__ csr, float* __restrict__ out, int N) {
  int t = blockIdx.x * 256 + threadIdx.x;
  int node = t / 10, l = t - node * 10;
  if (node >= N) return;
  int beg = rowptr[node], end = rowptr[node + 1];
  float a0 = 0.f, a1 = 0.f, a2 = 0.f, a3 = 0.f;
  for (int e = beg; e < end; ++e) {
    int s = csr[e];
    bf16x4 v = *(const bf16x4*)(p + (size_t)s * 40 + l * 4);
    a0 += (float)v[0]; a1 += (float)v[1]; a2 += (float)v[2]; a3 += (float)v[3];
  }
  float rd = (end > beg) ? 1.0f / (float)(end - beg) : 0.0f;
  float* o = out + (size_t)node * 40 + l * 4;
  float4 cur = *(const float4*)o;
  cur.x += a0 * rd;
  cur.y += a1 * rd;
  cur.z += a2 * rd;
  cur.w += a3 * rd;
  *(float4*)o = cur;
}

extern "C" void kernel_launch(void* const* d_in, const int* in_sizes, int n_in,
                              void* d_out, int out_size, void* d_ws, size_t ws_size,
                              hipStream_t stream) {
  const float* x    = (const float*)d_in[0];
  const int*   src1 = (const int*)d_in[1];
  const int*   dst1 = (const int*)d_in[2];
  const int*   src2 = (const int*)d_in[3];
  const int*   dst2 = (const int*)d_in[4];
  const float* ws1  = (const float*)d_in[5];
  const float* wn1  = (const float*)d_in[6];
  const float* b1   = (const float*)d_in[7];
  const float* ws2  = (const float*)d_in[8];
  const float* wn2  = (const float*)d_in[9];
  const float* b2   = (const float*)d_in[10];
  float*       out  = (float*)d_out;

  const int N = in_sizes[0] / D_IN;
  const int E = in_sizes[1];
  if (ws_size < WS_NEEDED) return;

  char*     ws   = (char*)d_ws;
  int*      hg1  = (int*)(ws + HG1_OFF);
  int*      hg2  = (int*)(ws + HG2_OFF);
  int*      bs1  = (int*)(ws + BS1_OFF);
  int*      bs2  = (int*)(ws + BS2_OFF);
  int*      rp1  = (int*)(ws + RP1_OFF);
  int*      rp2  = (int*)(ws + RP2_OFF);
  unsigned* bkt1 = (unsigned*)(ws + BKT1_OFF);
  unsigned* bkt2 = (unsigned*)(ws + BKT2_OFF);
  int*      csr1 = (int*)(ws + BKT1_OFF);     // aliases bkt1 (safe: see k_bcsr)
  int*      csr2 = (int*)(ws + BKT2_OFF);     // aliases bkt2
  bf16_t*   xcat = (bf16_t*)(ws + XCAT_OFF);
  bf16_t*   p    = (bf16_t*)(ws + P_OFF);
  bf16_t*   w1f  = (bf16_t*)(ws + W1F_OFF);
  bf16_t*   w2f  = (bf16_t*)(ws + W2F_OFF);

  const int nbkt  = (N + 255) >> 8;            // 391
  const int chunk = (E + NBLK - 1) / NBLK;     // 4688
  const int nsc   = nbkt * NBLK;               // 50048
  const int nscb  = (nsc + 255) / 256;         // 196 (<=512)
  const int nconvx = (N * 16 + 255) / 256;     // 6250

  k_prep<<<nconvx + 32 + 2 * NBLK, 256, 0, stream>>>(
      x, xcat, ws1, wn1, ws2, wn2, w1f, w2f, dst1, dst2, hg1, hg2,
      N, E, chunk, nbkt, nconvx);

  k_scan_block<<<dim3(nscb, 2), 256, 0, stream>>>(hg1, hg2, bs1, bs2, nsc);
  k_scan_sums<<<2, 512, 0, stream>>>(bs1, bs2, nscb);
  k_scan_add<<<dim3(nscb, 2), 256, 0, stream>>>(hg1, hg2, bs1, bs2, nsc);
  k_scat<<<dim3(NBLK, 2), 256, 0, stream>>>(src1, dst1, src2, dst2, hg1, hg2,
                                            bkt1, bkt2, E, chunk, nbkt);
  k_bcsr<<<dim3(nbkt, 2), 256, 0, stream>>>(hg1, hg2, bkt1, bkt2, csr1, csr2,
                                            rp1, rp2, E, N, nbkt);

  k_agg1<<<(N * 16 + 255) / 256, 256, 0, stream>>>(xcat, rp1, csr1, N);
  k_fused<<<(N + 127) / 128, 256, 0, stream>>>(xcat, w1f, b1, w2f, b2, out, p, N);
  k_agg2fin<<<(N * 10 + 255) / 256, 256, 0, stream>>>(p, rp2, csr2, out, N);
}

// Round 12
// 141.817 us; speedup vs baseline: 1.2996x; 1.2306x over previous
//
#include <hip/hip_runtime.h>
#include <hip/hip_bf16.h>
#include <cstdint>
#include <cstddef>

// ---------------------------------------------------------------------------
// GraphSAGE 2-layer forward (mean aggregator), MI355X / gfx950.
//
//   h  = relu(x @ Ws1.T + mean_nbr1(x) @ Wn1.T + b1)
//   out = h @ Ws2.T + mean_nbr2(h) @ Wn2.T + b2
//
// Structure (round 12):
//   k_prep (merged): xcat[:,0:128]=bf16(x); w1f/w2f frag-major bf16;
//                    per-chunk LDS bucket histograms (dst>>8)
//   k_scan_block + k_scan_addsums: hierarchical scan (sums-scan folded into
//                    the add pass — each block re-scans the 196 sums in LDS)
//   k_scat/k_bcsr:   atomic-free counting sort -> CSR
//   k_agg1:          xcat[:,128:256] = bf16(mean1(x)); 4-WAY UNROLLED
//                    neighbor loop (4 independent row loads in flight)
//   k_fused:         round-9 kernel (best measured: 46us): 128-row tile,
//                    LDS-staged A, swapped-operand MFMA, bf16x4 h + p
//   k_agg2fin:       out += mean2(p); 4-way unrolled bf16 gather
//
// Round-1: fp32-atomic scatter = atomic-bound -> CSR gather.
// Round-3: global-atomic CSR fill = HBM RMW -> LDS counting sort.
// Round-5..11: k_fused INVARIANT ~46us across 7 structural variants
//   (occupancy 8-28%, VGPR 64-176, tiles 64/128, 0-3 barriers, weight
//   traffic 2x). MFMA-busy ~6.5us in all => short-K GEMM shape limit for
//   this family. Amdahl: 70% of runtime is the OTHER kernels -> this round
//   optimizes the gathers (latency-chain unroll) + launch count.
// ---------------------------------------------------------------------------

#define D_IN 128
#define D_H  256
#define D_C  40

#define NBLK     128
#define NBKT_MAX 392
#define BKT_CAP  2560

typedef __bf16 bf16_t;
typedef __attribute__((ext_vector_type(8))) __bf16 bf16x8;
typedef __attribute__((ext_vector_type(4))) __bf16 bf16x4;
typedef __attribute__((ext_vector_type(4))) float  f32x4;

// ---------------- ws layout (bytes), 256B-aligned ----------------
static constexpr size_t NMAX = 100000;
static constexpr size_t EMAX = 600000;
static constexpr size_t NSC_MAX = (size_t)NBKT_MAX * NBLK;
static constexpr size_t alignup(size_t v) { return (v + 255) & ~size_t(255); }

static constexpr size_t HG1_OFF  = 0;
static constexpr size_t HG2_OFF  = alignup(HG1_OFF + NSC_MAX * 4);
static constexpr size_t BS1_OFF  = alignup(HG2_OFF + NSC_MAX * 4);
static constexpr size_t BS2_OFF  = alignup(BS1_OFF + 512 * 4);
static constexpr size_t RP1_OFF  = alignup(BS2_OFF + 512 * 4);
static constexpr size_t RP2_OFF  = alignup(RP1_OFF + (NMAX + 1) * 4);
static constexpr size_t BKT1_OFF = alignup(RP2_OFF + (NMAX + 1) * 4);
static constexpr size_t BKT2_OFF = alignup(BKT1_OFF + EMAX * 4);
static constexpr size_t XCAT_OFF = alignup(BKT2_OFF + EMAX * 4);        // bf16[N+128][256]
static constexpr size_t P_OFF    = alignup(XCAT_OFF + (NMAX + 128) * 256 * 2); // bf16[N][40]
static constexpr size_t W1F_OFF  = alignup(P_OFF + NMAX * 40 * 2);
static constexpr size_t W2F_OFF  = alignup(W1F_OFF + 32 * 256 * 8 * 2);
static constexpr size_t WS_NEEDED = W2F_OFF + 32 * 80 * 8 * 2;

// ---------------- merged prep: convx + conv_w + hist ----------------
__global__ __launch_bounds__(256) void k_prep(
    const float* __restrict__ x, bf16_t* __restrict__ xcat,
    const float* __restrict__ ws1, const float* __restrict__ wn1,
    const float* __restrict__ ws2, const float* __restrict__ wn2,
    bf16_t* __restrict__ w1f, bf16_t* __restrict__ w2f,
    const int* __restrict__ dst1, const int* __restrict__ dst2,
    int* __restrict__ hg1, int* __restrict__ hg2,
    int N, int E, int chunk, int nbkt, int nconvx) {
  __shared__ int h[NBKT_MAX];
  int bid = blockIdx.x;

  if (bid < nconvx) {                       // ---- x -> bf16 into xcat[:,0:128]
    int t = bid * 256 + threadIdx.x;
    if (t < N * 16) {
      int row = t >> 4, j = t & 15;
      const float* sp = x + (size_t)row * 128 + j * 8;
      float4 v0 = ((const float4*)sp)[0];
      float4 v1 = ((const float4*)sp)[1];
      bf16x8 o;
      o[0] = (bf16_t)v0.x; o[1] = (bf16_t)v0.y; o[2] = (bf16_t)v0.z; o[3] = (bf16_t)v0.w;
      o[4] = (bf16_t)v1.x; o[5] = (bf16_t)v1.y; o[6] = (bf16_t)v1.z; o[7] = (bf16_t)v1.w;
      *(bf16x8*)(xcat + (size_t)row * 256 + j * 8) = o;
    }
    return;
  }
  bid -= nconvx;

  if (bid < 32) {                           // ---- weights -> bf16 frag-major
    int t = bid * 256 + threadIdx.x;
    {
      int ks4g = t >> 8, col = t & 255;
      int k0 = (ks4g >> 2) * 32 + (ks4g & 3) * 8;
      bf16x8 o;
#pragma unroll
      for (int i = 0; i < 8; ++i) {
        int k = k0 + i;   // K-concat: k<128 -> Ws1, else Wn1
        float v = (k < 128) ? ws1[col * 128 + k] : wn1[col * 128 + (k - 128)];
        o[i] = (bf16_t)v;
      }
      *(bf16x8*)(w1f + (size_t)t * 8) = o;
    }
    if (t < 32 * 80) {
      int ks4g = t / 80, col = t - ks4g * 80;
      int k0 = (ks4g >> 2) * 32 + (ks4g & 3) * 8;
      bf16x8 o;
#pragma unroll
      for (int i = 0; i < 8; ++i) {
        int k = k0 + i;   // col-concat: col<40 -> Ws2, else Wn2
        float v = (col < 40) ? ws2[col * 256 + k] : wn2[(col - 40) * 256 + k];
        o[i] = (bf16_t)v;
      }
      *(bf16x8*)(w2f + (size_t)t * 8) = o;
    }
    return;
  }
  bid -= 32;                                 // ---- histogram
  {
    const int* dst = (bid >> 7) ? dst2 : dst1;
    int*       hg  = (bid >> 7) ? hg2 : hg1;
    int        cb  = bid & 127;
    for (int i = threadIdx.x; i < nbkt; i += 256) h[i] = 0;
    __syncthreads();
    int beg = cb * chunk, end = min(E, beg + chunk);
    for (int e = beg + threadIdx.x; e < end; e += 256)
      atomicAdd(&h[dst[e] >> 8], 1);
    __syncthreads();
    for (int b = threadIdx.x; b < nbkt; b += 256)
      hg[b * NBLK + cb] = h[b];   // bucket-major, chunk-minor
  }
}

// ---------------- scan pass 1: per-256-chunk exclusive scan + chunk totals ----
__global__ void k_scan_block(int* __restrict__ a1, int* __restrict__ a2,
                             int* __restrict__ b1s, int* __restrict__ b2s, int n) {
  int* a    = blockIdx.y ? a2 : a1;
  int* bsum = blockIdx.y ? b2s : b1s;
  __shared__ int lds[256];
  int t = threadIdx.x, i = blockIdx.x * 256 + t;
  int v = (i < n) ? a[i] : 0;
  lds[t] = v;
  __syncthreads();
  for (int off = 1; off < 256; off <<= 1) {
    int add = (t >= off) ? lds[t - off] : 0;
    __syncthreads();
    lds[t] += add;
    __syncthreads();
  }
  if (i < n) a[i] = lds[t] - v;
  if (t == 255) bsum[blockIdx.x] = lds[255];
}

// ---------------- scan pass 2 (merged): each block re-scans the <=256 chunk
// totals in LDS (redundant, trivial) and adds the exclusive prefix. ----------
__global__ void k_scan_addsums(int* __restrict__ a1, int* __restrict__ a2,
                               const int* __restrict__ b1s, const int* __restrict__ b2s,
                               int n, int nb) {
  int* a          = blockIdx.y ? a2 : a1;
  const int* bsum = blockIdx.y ? b2s : b1s;
  __shared__ int lds[256];
  int t = threadIdx.x;
  int v = (t < nb) ? bsum[t] : 0;
  lds[t] = v;
  __syncthreads();
  for (int off = 1; off < 256; off <<= 1) {
    int add = (t >= off) ? lds[t - off] : 0;
    __syncthreads();
    lds[t] += add;
    __syncthreads();
  }
  __shared__ int excl[256];
  excl[t] = lds[t] - v;
  __syncthreads();
  int i = blockIdx.x * 256 + t;
  if (i < n) a[i] += excl[i >> 8];
}

// ---------------- scatter into bucketed array (LDS cursors) ----------------
__global__ void k_scat(const int* __restrict__ src1, const int* __restrict__ dst1,
                       const int* __restrict__ src2, const int* __restrict__ dst2,
                       const int* __restrict__ off1, const int* __restrict__ off2,
                       unsigned* __restrict__ bkt1, unsigned* __restrict__ bkt2,
                       int E, int chunk, int nbkt) {
  const int* src = blockIdx.y ? src2 : src1;
  const int* dst = blockIdx.y ? dst2 : dst1;
  const int* off = blockIdx.y ? off2 : off1;
  unsigned*  bkt = blockIdx.y ? bkt2 : bkt1;
  __shared__ int cur[NBKT_MAX];
  for (int i = threadIdx.x; i < nbkt; i += 256)
    cur[i] = off[i * NBLK + blockIdx.x];
  __syncthreads();
  int beg = blockIdx.x * chunk, end = min(E, beg + chunk);
  for (int e = beg + threadIdx.x; e < end; e += 256) {
    int d = dst[e];
    int slot = atomicAdd(&cur[d >> 8], 1);
    bkt[slot] = (unsigned)src[e] | ((unsigned)(d & 255) << 24);
  }
}

// ---------------- per-bucket LDS counting sort -> CSR + rowptr ----------------
__global__ __launch_bounds__(256) void k_bcsr(
    const int* __restrict__ off1, const int* __restrict__ off2,
    const unsigned* bkt1, const unsigned* bkt2,
    int* csr1, int* csr2,
    int* __restrict__ rp1, int* __restrict__ rp2, int E, int N, int nbkt) {
  const int* off      = blockIdx.y ? off2 : off1;
  const unsigned* bkt = blockIdx.y ? bkt2 : bkt1;
  int* csr            = blockIdx.y ? csr2 : csr1;
  int* rowptr         = blockIdx.y ? rp2 : rp1;

  const int b = blockIdx.x, t = threadIdx.x;
  const int base = off[b * NBLK];
  const int endp = (b == nbkt - 1) ? E : off[(b + 1) * NBLK];
  const int cnt  = endp - base;

  __shared__ int hist[256];
  __shared__ int sc[256];
  __shared__ int cur[256];
  __shared__ int stage[BKT_CAP];

  hist[t] = 0;
  __syncthreads();
  for (int i = t; i < cnt; i += 256)
    atomicAdd(&hist[bkt[base + i] >> 24], 1);
  __syncthreads();

  int v = hist[t];
  sc[t] = v;
  __syncthreads();
  for (int off_ = 1; off_ < 256; off_ <<= 1) {
    int add = (t >= off_) ? sc[t - off_] : 0;
    __syncthreads();
    sc[t] += add;
    __syncthreads();
  }
  int excl = sc[t] - v;

  int node = b * 256 + t;
  if (node < N) rowptr[node] = base + excl;
  if (b == nbkt - 1 && t == 0) rowptr[N] = E;
  cur[t] = excl;
  __syncthreads();

  for (int i = t; i < cnt; i += 256) {
    unsigned u = bkt[base + i];
    int slot = atomicAdd(&cur[u >> 24], 1);
    if (slot < BKT_CAP) stage[slot] = (int)(u & 0xFFFFFFu);
  }
  __syncthreads();
  for (int i = t; i < cnt; i += 256)
    csr[base + i] = stage[i];
}

// ---------------- layer-1 mean -> xcat[:,128:256]; 4-way unrolled gather ------
// 16 lanes/node, bf16x8/lane. 4 independent neighbor-row loads in flight per
// iteration (gather is a latency chain; avg degree ~6, L3 latency ~500cyc).
__global__ void k_agg1(bf16_t* __restrict__ xcat, const int* __restrict__ rowptr,
                       const int* __restrict__ csr, int N) {
  int t = blockIdx.x * 256 + threadIdx.x;
  int node = t >> 4, l = t & 15;
  if (node >= N) return;
  int beg = rowptr[node], end = rowptr[node + 1];
  float acc[8] = {0.f, 0.f, 0.f, 0.f, 0.f, 0.f, 0.f, 0.f};
  int e = beg;
  for (; e + 4 <= end; e += 4) {
    int s0 = csr[e], s1 = csr[e + 1], s2 = csr[e + 2], s3 = csr[e + 3];
    bf16x8 v0 = *(const bf16x8*)(xcat + (size_t)s0 * 256 + l * 8);
    bf16x8 v1 = *(const bf16x8*)(xcat + (size_t)s1 * 256 + l * 8);
    bf16x8 v2 = *(const bf16x8*)(xcat + (size_t)s2 * 256 + l * 8);
    bf16x8 v3 = *(const bf16x8*)(xcat + (size_t)s3 * 256 + l * 8);
#pragma unroll
    for (int i = 0; i < 8; ++i)
      acc[i] += (float)v0[i] + (float)v1[i] + (float)v2[i] + (float)v3[i];
  }
  for (; e < end; ++e) {
    int s = csr[e];
    bf16x8 v = *(const bf16x8*)(xcat + (size_t)s * 256 + l * 8);
#pragma unroll
    for (int i = 0; i < 8; ++i) acc[i] += (float)v[i];
  }
  float rd = (end > beg) ? 1.0f / (float)(end - beg) : 0.0f;
  bf16x8 o;
#pragma unroll
  for (int i = 0; i < 8; ++i) o[i] = (bf16_t)(acc[i] * rd);
  *(bf16x8*)(xcat + (size_t)node * 256 + 128 + l * 8) = o;
}

// ---------------- fused GEMM (round-9, best measured): 128-row tile ----------
__global__ __launch_bounds__(256, 2) void k_fused(
    const bf16_t* __restrict__ xcat, const bf16_t* __restrict__ w1f,
    const float* __restrict__ b1, const bf16_t* __restrict__ w2f,
    const float* __restrict__ b2v, float* __restrict__ out,
    bf16_t* __restrict__ p, int N) {
  __shared__ __align__(16) char lds[65536];
  const int tid  = (int)threadIdx.x;
  const int wv   = tid >> 6;
  const int lane = tid & 63;
  const int lr   = lane & 15;
  const int lg   = lane >> 4;
  const int c0   = wv * 64;
  const int m0   = (int)blockIdx.x * 128;

  // ---- stage A-tile: 16 x global_load_lds dwordx4, pre-swizzled source ----
  {
    const char* tb = (const char*)(xcat + (size_t)m0 * 256);
#pragma unroll
    for (int i = 0; i < 16; ++i) {
      int L   = i * 4096 + tid * 16;
      int row = L >> 9;
      int c   = L & 511;
      int so  = (row << 9) | (c ^ ((row & 7) << 4));
      __builtin_amdgcn_global_load_lds(
          (const __attribute__((address_space(1))) void*)(tb + so),
          (__attribute__((address_space(3))) void*)(lds + L), 16, 0, 0);
    }
  }
  __syncthreads();

  // ---- phase A: acc[wb][rb] = sum_ks mfma(w1[wb], x[rb]) ----
  f32x4 acc[4][8] = {};
#pragma unroll
  for (int ks = 0; ks < 8; ++ks) {
    bf16x8 wf[4];
#pragma unroll
    for (int wb = 0; wb < 4; ++wb)
      wf[wb] = *(const bf16x8*)(w1f + ((size_t)(ks * 4 + lg) * 256 +
                                       (c0 + wb * 16 + lr)) * 8);
    bf16x8 ax[8];
#pragma unroll
    for (int rb = 0; rb < 8; ++rb) {
      int lrow = rb * 16 + lr;
      ax[rb] = *(const bf16x8*)(lds + lrow * 512 +
                                ((ks * 64 + lg * 16) ^ ((lrow & 7) << 4)));
    }
#pragma unroll
    for (int wb = 0; wb < 4; ++wb)
#pragma unroll
      for (int rb = 0; rb < 8; ++rb)
        acc[wb][rb] = __builtin_amdgcn_mfma_f32_16x16x32_bf16(
            wf[wb], ax[rb], acc[wb][rb], 0, 0, 0);
  }

  __syncthreads();

  // ---- epilogue A: h = relu(acc+b1) -> packed bf16x4 ----
#pragma unroll
  for (int wb = 0; wb < 4; ++wb) {
    float4 b4 = *(const float4*)(b1 + c0 + wb * 16 + lg * 4);
#pragma unroll
    for (int rb = 0; rb < 8; ++rb) {
      int xrow = rb * 16 + lr;
      bf16x4 o;
      o[0] = (bf16_t)fmaxf(acc[wb][rb][0] + b4.x, 0.f);
      o[1] = (bf16_t)fmaxf(acc[wb][rb][1] + b4.y, 0.f);
      o[2] = (bf16_t)fmaxf(acc[wb][rb][2] + b4.z, 0.f);
      o[3] = (bf16_t)fmaxf(acc[wb][rb][3] + b4.w, 0.f);
      *(bf16x4*)(lds + xrow * 512 +
                 ((c0 * 2 + wb * 32 + lg * 8) ^ ((xrow & 7) << 4))) = o;
    }
  }
  __syncthreads();

  // ---- phase B: wave owns rows wv*32..wv*32+31 ----
  f32x4 acc2[2][5] = {};
#pragma unroll
  for (int ks = 0; ks < 8; ++ks) {
    bf16x8 hf[2];
#pragma unroll
    for (int m = 0; m < 2; ++m) {
      int arow = wv * 32 + m * 16 + lr;
      hf[m] = *(const bf16x8*)(lds + arow * 512 +
                               ((ks * 64 + lg * 16) ^ ((arow & 7) << 4)));
    }
#pragma unroll
    for (int wb = 0; wb < 5; ++wb) {
      bf16x8 w2 = *(const bf16x8*)(w2f + ((size_t)(ks * 4 + lg) * 80 +
                                          (wb * 16 + lr)) * 8);
#pragma unroll
      for (int m = 0; m < 2; ++m)
        acc2[m][wb] = __builtin_amdgcn_mfma_f32_16x16x32_bf16(
            w2, hf[m], acc2[m][wb], 0, 0, 0);
    }
  }

#pragma unroll
  for (int m = 0; m < 2; ++m) {
    const int r = m0 + wv * 32 + m * 16 + lr;
    if (r < N) {
#pragma unroll
      for (int wb = 0; wb < 5; ++wb) {
        int col0 = wb * 16 + lg * 4;
        f32x4 v = acc2[m][wb];
        if (col0 < 40) {
          float4 b4 = *(const float4*)(b2v + col0);
          v[0] += b4.x; v[1] += b4.y; v[2] += b4.z; v[3] += b4.w;
          *(f32x4*)(out + (size_t)r * 40 + col0) = v;
        } else {
          bf16x4 o;
          o[0] = (bf16_t)v[0]; o[1] = (bf16_t)v[1];
          o[2] = (bf16_t)v[2]; o[3] = (bf16_t)v[3];
          *(bf16x4*)(p + (size_t)r * 40 + (col0 - 40)) = o;
        }
      }
    }
  }
}

// ---------------- layer-2 mean: out += mean2(p); 4-way unrolled bf16 gather ---
__global__ void k_agg2fin(const bf16_t* __restrict__ p, const int* __restrict__ rowptr,
                          const int* __restrict__ csr, float* __restrict__ out, int N) {
  int t = blockIdx.x * 256 + threadIdx.x;
  int node = t / 10, l = t - node * 10;
  if (node >= N) return;
  int beg = rowptr[node], end = rowptr[node + 1];
  float a0 = 0.f, a1 = 0.f, a2 = 0.f, a3 = 0.f;
  int e = beg;
  for (; e + 4 <= end; e += 4) {
    int s0 = csr[e], s1 = csr[e + 1], s2 = csr[e + 2], s3 = csr[e + 3];
    bf16x4 v0 = *(const bf16x4*)(p + (size_t)s0 * 40 + l * 4);
    bf16x4 v1 = *(const bf16x4*)(p + (size_t)s1 * 40 + l * 4);
    bf16x4 v2 = *(const bf16x4*)(p + (size_t)s2 * 40 + l * 4);
    bf16x4 v3 = *(const bf16x4*)(p + (size_t)s3 * 40 + l * 4);
    a0 += (float)v0[0] + (float)v1[0] + (float)v2[0] + (float)v3[0];
    a1 += (float)v0[1] + (float)v1[1] + (float)v2[1] + (float)v3[1];
    a2 += (float)v0[2] + (float)v1[2] + (float)v2[2] + (float)v3[2];
    a3 += (float)v0[3] + (float)v1[3] + (float)v2[3] + (float)v3[3];
  }
  for (; e < end; ++e) {
    int s = csr[e];
    bf16x4 v = *(const bf16x4*)(p + (size_t)s * 40 + l * 4);
    a0 += (float)v[0]; a1 += (float)v[1]; a2 += (float)v[2]; a3 += (float)v[3];
  }
  float rd = (end > beg) ? 1.0f / (float)(end - beg) : 0.0f;
  float* o = out + (size_t)node * 40 + l * 4;
  float4 cur = *(const float4*)o;
  cur.x += a0 * rd;
  cur.y += a1 * rd;
  cur.z += a2 * rd;
  cur.w += a3 * rd;
  *(float4*)o = cur;
}

extern "C" void kernel_launch(void* const* d_in, const int* in_sizes, int n_in,
                              void* d_out, int out_size, void* d_ws, size_t ws_size,
                              hipStream_t stream) {
  const float* x    = (const float*)d_in[0];
  const int*   src1 = (const int*)d_in[1];
  const int*   dst1 = (const int*)d_in[2];
  const int*   src2 = (const int*)d_in[3];
  const int*   dst2 = (const int*)d_in[4];
  const float* ws1  = (const float*)d_in[5];
  const float* wn1  = (const float*)d_in[6];
  const float* b1   = (const float*)d_in[7];
  const float* ws2  = (const float*)d_in[8];
  const float* wn2  = (const float*)d_in[9];
  const float* b2   = (const float*)d_in[10];
  float*       out  = (float*)d_out;

  const int N = in_sizes[0] / D_IN;
  const int E = in_sizes[1];
  if (ws_size < WS_NEEDED) return;

  char*     ws   = (char*)d_ws;
  int*      hg1  = (int*)(ws + HG1_OFF);
  int*      hg2  = (int*)(ws + HG2_OFF);
  int*      bs1  = (int*)(ws + BS1_OFF);
  int*      bs2  = (int*)(ws + BS2_OFF);
  int*      rp1  = (int*)(ws + RP1_OFF);
  int*      rp2  = (int*)(ws + RP2_OFF);
  unsigned* bkt1 = (unsigned*)(ws + BKT1_OFF);
  unsigned* bkt2 = (unsigned*)(ws + BKT2_OFF);
  int*      csr1 = (int*)(ws + BKT1_OFF);     // aliases bkt1 (safe: see k_bcsr)
  int*      csr2 = (int*)(ws + BKT2_OFF);     // aliases bkt2
  bf16_t*   xcat = (bf16_t*)(ws + XCAT_OFF);
  bf16_t*   p    = (bf16_t*)(ws + P_OFF);
  bf16_t*   w1f  = (bf16_t*)(ws + W1F_OFF);
  bf16_t*   w2f  = (bf16_t*)(ws + W2F_OFF);

  const int nbkt  = (N + 255) >> 8;            // 391
  const int chunk = (E + NBLK - 1) / NBLK;     // 4688
  const int nsc   = nbkt * NBLK;               // 50048
  const int nscb  = (nsc + 255) / 256;         // 196 (<=256)
  const int nconvx = (N * 16 + 255) / 256;     // 6250
  const int ntiles = (N + 127) / 128;          // 782

  k_prep<<<nconvx + 32 + 2 * NBLK, 256, 0, stream>>>(
      x, xcat, ws1, wn1, ws2, wn2, w1f, w2f, dst1, dst2, hg1, hg2,
      N, E, chunk, nbkt, nconvx);

  k_scan_block<<<dim3(nscb, 2), 256, 0, stream>>>(hg1, hg2, bs1, bs2, nsc);
  k_scan_addsums<<<dim3(nscb, 2), 256, 0, stream>>>(hg1, hg2, bs1, bs2, nsc, nscb);
  k_scat<<<dim3(NBLK, 2), 256, 0, stream>>>(src1, dst1, src2, dst2, hg1, hg2,
                                            bkt1, bkt2, E, chunk, nbkt);
  k_bcsr<<<dim3(nbkt, 2), 256, 0, stream>>>(hg1, hg2, bkt1, bkt2, csr1, csr2,
                                            rp1, rp2, E, N, nbkt);

  k_agg1<<<(N * 16 + 255) / 256, 256, 0, stream>>>(xcat, rp1, csr1, N);
  k_fused<<<ntiles, 256, 0, stream>>>(xcat, w1f, b1, w2f, b2, out, p, N);
  k_agg2fin<<<(N * 10 + 255) / 256, 256, 0, stream>>>(p, rp2, csr2, out, N);
}

// Round 13
// 136.470 us; speedup vs baseline: 1.3505x; 1.0392x over previous
//
#include <hip/hip_runtime.h>
#include <hip/hip_bf16.h>
#include <cstdint>
#include <cstddef>

// ---------------------------------------------------------------------------
// GraphSAGE 2-layer forward (mean aggregator), MI355X / gfx950.
//
//   h  = relu(x @ Ws1.T + mean_nbr1(x) @ Wn1.T + b1)
//   out = h @ Ws2.T + mean_nbr2(h) @ Wn2.T + b2
//
// Structure (round 13):
//   k_prep / scans / scat / bcsr / agg1 / agg2fin: unchanged from round 12.
//   k_fused: 64-row tile, 4 waves, 32KB LDS, with EXPLICIT DEPTH-2 REGISTER
//     DOUBLE-BUFFERING of all in-loop loads (w1/ax in phase A, w2/hf in
//     phase B): next-ks loads are issued before current-ks MFMAs, with
//     launch_bounds(256,3) leaving ~100 VGPRs of headroom so the scheduler
//     can actually keep them in flight.
//
// Round-1: fp32-atomic scatter = atomic-bound -> CSR gather.
// Round-3: global-atomic CSR fill = HBM RMW -> LDS counting sort.
// Round-5..11: k_fused invariant ~46us. Round-13 re-diagnosis: VGPR_Count
//   128 == acc size -> ZERO headroom -> every L2 weight load serialized
//   (~72 loads x ~500cyc = 36K cyc/block = the entire block time). All
//   prior variants were register-starved (r5/r8 cap too low, r7 spilled,
//   r9 acc=128). Fix: small acc (64) + explicit depth-2 load pipeline.
// Round-12: gather 4-way unroll + scan merge: 153 -> 142us.
// ---------------------------------------------------------------------------

#define D_IN 128
#define D_H  256
#define D_C  40

#define NBLK     128
#define NBKT_MAX 392
#define BKT_CAP  2560

typedef __bf16 bf16_t;
typedef __attribute__((ext_vector_type(8))) __bf16 bf16x8;
typedef __attribute__((ext_vector_type(4))) __bf16 bf16x4;
typedef __attribute__((ext_vector_type(4))) float  f32x4;

// ---------------- ws layout (bytes), 256B-aligned ----------------
static constexpr size_t NMAX = 100000;
static constexpr size_t EMAX = 600000;
static constexpr size_t NSC_MAX = (size_t)NBKT_MAX * NBLK;
static constexpr size_t alignup(size_t v) { return (v + 255) & ~size_t(255); }

static constexpr size_t HG1_OFF  = 0;
static constexpr size_t HG2_OFF  = alignup(HG1_OFF + NSC_MAX * 4);
static constexpr size_t BS1_OFF  = alignup(HG2_OFF + NSC_MAX * 4);
static constexpr size_t BS2_OFF  = alignup(BS1_OFF + 512 * 4);
static constexpr size_t RP1_OFF  = alignup(BS2_OFF + 512 * 4);
static constexpr size_t RP2_OFF  = alignup(RP1_OFF + (NMAX + 1) * 4);
static constexpr size_t BKT1_OFF = alignup(RP2_OFF + (NMAX + 1) * 4);
static constexpr size_t BKT2_OFF = alignup(BKT1_OFF + EMAX * 4);
static constexpr size_t XCAT_OFF = alignup(BKT2_OFF + EMAX * 4);        // bf16[N+128][256]
static constexpr size_t P_OFF    = alignup(XCAT_OFF + (NMAX + 128) * 256 * 2); // bf16[N][40]
static constexpr size_t W1F_OFF  = alignup(P_OFF + NMAX * 40 * 2);
static constexpr size_t W2F_OFF  = alignup(W1F_OFF + 32 * 256 * 8 * 2);
static constexpr size_t WS_NEEDED = W2F_OFF + 32 * 80 * 8 * 2;

// ---------------- merged prep: convx + conv_w + hist ----------------
__global__ __launch_bounds__(256) void k_prep(
    const float* __restrict__ x, bf16_t* __restrict__ xcat,
    const float* __restrict__ ws1, const float* __restrict__ wn1,
    const float* __restrict__ ws2, const float* __restrict__ wn2,
    bf16_t* __restrict__ w1f, bf16_t* __restrict__ w2f,
    const int* __restrict__ dst1, const int* __restrict__ dst2,
    int* __restrict__ hg1, int* __restrict__ hg2,
    int N, int E, int chunk, int nbkt, int nconvx) {
  __shared__ int h[NBKT_MAX];
  int bid = blockIdx.x;

  if (bid < nconvx) {
    int t = bid * 256 + threadIdx.x;
    if (t < N * 16) {
      int row = t >> 4, j = t & 15;
      const float* sp = x + (size_t)row * 128 + j * 8;
      float4 v0 = ((const float4*)sp)[0];
      float4 v1 = ((const float4*)sp)[1];
      bf16x8 o;
      o[0] = (bf16_t)v0.x; o[1] = (bf16_t)v0.y; o[2] = (bf16_t)v0.z; o[3] = (bf16_t)v0.w;
      o[4] = (bf16_t)v1.x; o[5] = (bf16_t)v1.y; o[6] = (bf16_t)v1.z; o[7] = (bf16_t)v1.w;
      *(bf16x8*)(xcat + (size_t)row * 256 + j * 8) = o;
    }
    return;
  }
  bid -= nconvx;

  if (bid < 32) {
    int t = bid * 256 + threadIdx.x;
    {
      int ks4g = t >> 8, col = t & 255;
      int k0 = (ks4g >> 2) * 32 + (ks4g & 3) * 8;
      bf16x8 o;
#pragma unroll
      for (int i = 0; i < 8; ++i) {
        int k = k0 + i;
        float v = (k < 128) ? ws1[col * 128 + k] : wn1[col * 128 + (k - 128)];
        o[i] = (bf16_t)v;
      }
      *(bf16x8*)(w1f + (size_t)t * 8) = o;
    }
    if (t < 32 * 80) {
      int ks4g = t / 80, col = t - ks4g * 80;
      int k0 = (ks4g >> 2) * 32 + (ks4g & 3) * 8;
      bf16x8 o;
#pragma unroll
      for (int i = 0; i < 8; ++i) {
        int k = k0 + i;
        float v = (col < 40) ? ws2[col * 256 + k] : wn2[(col - 40) * 256 + k];
        o[i] = (bf16_t)v;
      }
      *(bf16x8*)(w2f + (size_t)t * 8) = o;
    }
    return;
  }
  bid -= 32;
  {
    const int* dst = (bid >> 7) ? dst2 : dst1;
    int*       hg  = (bid >> 7) ? hg2 : hg1;
    int        cb  = bid & 127;
    for (int i = threadIdx.x; i < nbkt; i += 256) h[i] = 0;
    __syncthreads();
    int beg = cb * chunk, end = min(E, beg + chunk);
    for (int e = beg + threadIdx.x; e < end; e += 256)
      atomicAdd(&h[dst[e] >> 8], 1);
    __syncthreads();
    for (int b = threadIdx.x; b < nbkt; b += 256)
      hg[b * NBLK + cb] = h[b];
  }
}

// ---------------- scan pass 1 ----------------
__global__ void k_scan_block(int* __restrict__ a1, int* __restrict__ a2,
                             int* __restrict__ b1s, int* __restrict__ b2s, int n) {
  int* a    = blockIdx.y ? a2 : a1;
  int* bsum = blockIdx.y ? b2s : b1s;
  __shared__ int lds[256];
  int t = threadIdx.x, i = blockIdx.x * 256 + t;
  int v = (i < n) ? a[i] : 0;
  lds[t] = v;
  __syncthreads();
  for (int off = 1; off < 256; off <<= 1) {
    int add = (t >= off) ? lds[t - off] : 0;
    __syncthreads();
    lds[t] += add;
    __syncthreads();
  }
  if (i < n) a[i] = lds[t] - v;
  if (t == 255) bsum[blockIdx.x] = lds[255];
}

// ---------------- scan pass 2 (merged sums-scan + add) ----------------
__global__ void k_scan_addsums(int* __restrict__ a1, int* __restrict__ a2,
                               const int* __restrict__ b1s, const int* __restrict__ b2s,
                               int n, int nb) {
  int* a          = blockIdx.y ? a2 : a1;
  const int* bsum = blockIdx.y ? b2s : b1s;
  __shared__ int lds[256];
  int t = threadIdx.x;
  int v = (t < nb) ? bsum[t] : 0;
  lds[t] = v;
  __syncthreads();
  for (int off = 1; off < 256; off <<= 1) {
    int add = (t >= off) ? lds[t - off] : 0;
    __syncthreads();
    lds[t] += add;
    __syncthreads();
  }
  __shared__ int excl[256];
  excl[t] = lds[t] - v;
  __syncthreads();
  int i = blockIdx.x * 256 + t;
  if (i < n) a[i] += excl[i >> 8];
}

// ---------------- scatter into bucketed array (LDS cursors) ----------------
__global__ void k_scat(const int* __restrict__ src1, const int* __restrict__ dst1,
                       const int* __restrict__ src2, const int* __restrict__ dst2,
                       const int* __restrict__ off1, const int* __restrict__ off2,
                       unsigned* __restrict__ bkt1, unsigned* __restrict__ bkt2,
                       int E, int chunk, int nbkt) {
  const int* src = blockIdx.y ? src2 : src1;
  const int* dst = blockIdx.y ? dst2 : dst1;
  const int* off = blockIdx.y ? off2 : off1;
  unsigned*  bkt = blockIdx.y ? bkt2 : bkt1;
  __shared__ int cur[NBKT_MAX];
  for (int i = threadIdx.x; i < nbkt; i += 256)
    cur[i] = off[i * NBLK + blockIdx.x];
  __syncthreads();
  int beg = blockIdx.x * chunk, end = min(E, beg + chunk);
  for (int e = beg + threadIdx.x; e < end; e += 256) {
    int d = dst[e];
    int slot = atomicAdd(&cur[d >> 8], 1);
    bkt[slot] = (unsigned)src[e] | ((unsigned)(d & 255) << 24);
  }
}

// ---------------- per-bucket LDS counting sort -> CSR + rowptr ----------------
__global__ __launch_bounds__(256) void k_bcsr(
    const int* __restrict__ off1, const int* __restrict__ off2,
    const unsigned* bkt1, const unsigned* bkt2,
    int* csr1, int* csr2,
    int* __restrict__ rp1, int* __restrict__ rp2, int E, int N, int nbkt) {
  const int* off      = blockIdx.y ? off2 : off1;
  const unsigned* bkt = blockIdx.y ? bkt2 : bkt1;
  int* csr            = blockIdx.y ? csr2 : csr1;
  int* rowptr         = blockIdx.y ? rp2 : rp1;

  const int b = blockIdx.x, t = threadIdx.x;
  const int base = off[b * NBLK];
  const int endp = (b == nbkt - 1) ? E : off[(b + 1) * NBLK];
  const int cnt  = endp - base;

  __shared__ int hist[256];
  __shared__ int sc[256];
  __shared__ int cur[256];
  __shared__ int stage[BKT_CAP];

  hist[t] = 0;
  __syncthreads();
  for (int i = t; i < cnt; i += 256)
    atomicAdd(&hist[bkt[base + i] >> 24], 1);
  __syncthreads();

  int v = hist[t];
  sc[t] = v;
  __syncthreads();
  for (int off_ = 1; off_ < 256; off_ <<= 1) {
    int add = (t >= off_) ? sc[t - off_] : 0;
    __syncthreads();
    sc[t] += add;
    __syncthreads();
  }
  int excl = sc[t] - v;

  int node = b * 256 + t;
  if (node < N) rowptr[node] = base + excl;
  if (b == nbkt - 1 && t == 0) rowptr[N] = E;
  cur[t] = excl;
  __syncthreads();

  for (int i = t; i < cnt; i += 256) {
    unsigned u = bkt[base + i];
    int slot = atomicAdd(&cur[u >> 24], 1);
    if (slot < BKT_CAP) stage[slot] = (int)(u & 0xFFFFFFu);
  }
  __syncthreads();
  for (int i = t; i < cnt; i += 256)
    csr[base + i] = stage[i];
}

// ---------------- layer-1 mean; 4-way unrolled gather ----------------
__global__ void k_agg1(bf16_t* __restrict__ xcat, const int* __restrict__ rowptr,
                       const int* __restrict__ csr, int N) {
  int t = blockIdx.x * 256 + threadIdx.x;
  int node = t >> 4, l = t & 15;
  if (node >= N) return;
  int beg = rowptr[node], end = rowptr[node + 1];
  float acc[8] = {0.f, 0.f, 0.f, 0.f, 0.f, 0.f, 0.f, 0.f};
  int e = beg;
  for (; e + 4 <= end; e += 4) {
    int s0 = csr[e], s1 = csr[e + 1], s2 = csr[e + 2], s3 = csr[e + 3];
    bf16x8 v0 = *(const bf16x8*)(xcat + (size_t)s0 * 256 + l * 8);
    bf16x8 v1 = *(const bf16x8*)(xcat + (size_t)s1 * 256 + l * 8);
    bf16x8 v2 = *(const bf16x8*)(xcat + (size_t)s2 * 256 + l * 8);
    bf16x8 v3 = *(const bf16x8*)(xcat + (size_t)s3 * 256 + l * 8);
#pragma unroll
    for (int i = 0; i < 8; ++i)
      acc[i] += (float)v0[i] + (float)v1[i] + (float)v2[i] + (float)v3[i];
  }
  for (; e < end; ++e) {
    int s = csr[e];
    bf16x8 v = *(const bf16x8*)(xcat + (size_t)s * 256 + l * 8);
#pragma unroll
    for (int i = 0; i < 8; ++i) acc[i] += (float)v[i];
  }
  float rd = (end > beg) ? 1.0f / (float)(end - beg) : 0.0f;
  bf16x8 o;
#pragma unroll
  for (int i = 0; i < 8; ++i) o[i] = (bf16_t)(acc[i] * rd);
  *(bf16x8*)(xcat + (size_t)node * 256 + 128 + l * 8) = o;
}

// ---------------- fused GEMM: 64-row tile + depth-2 register pipeline --------
// acc[4][4]=64 VGPR leaves ~100 regs headroom at (256,3) so next-ks loads
// (w1/ax, w2/hf) stay in flight across the current ks's MFMA block.
// Swizzle (involution): byte-in-row c -> c ^ ((row&7)<<4) on staged A and h.
__global__ __launch_bounds__(256, 3) void k_fused(
    const bf16_t* __restrict__ xcat, const bf16_t* __restrict__ w1f,
    const float* __restrict__ b1, const bf16_t* __restrict__ w2f,
    const float* __restrict__ b2v, float* __restrict__ out,
    bf16_t* __restrict__ p, int N) {
  __shared__ __align__(16) char lds[32768];
  const int tid  = (int)threadIdx.x;
  const int wv   = tid >> 6;
  const int lane = tid & 63;
  const int lr   = lane & 15;
  const int lg   = lane >> 4;
  const int c0   = wv * 64;
  const int m0   = (int)blockIdx.x * 64;

  // ---- stage A-tile: 8 x global_load_lds dwordx4, pre-swizzled source ----
  {
    const char* tb = (const char*)(xcat + (size_t)m0 * 256);
#pragma unroll
    for (int i = 0; i < 8; ++i) {
      int L   = i * 4096 + tid * 16;
      int row = L >> 9;
      int c   = L & 511;
      int so  = (row << 9) | (c ^ ((row & 7) << 4));
      __builtin_amdgcn_global_load_lds(
          (const __attribute__((address_space(1))) void*)(tb + so),
          (__attribute__((address_space(3))) void*)(lds + L), 16, 0, 0);
    }
  }

  // preload ks=0 weights (global; independent of the LDS staging)
  bf16x8 wfc[4];
#pragma unroll
  for (int wb = 0; wb < 4; ++wb)
    wfc[wb] = *(const bf16x8*)(w1f + ((size_t)(0 * 4 + lg) * 256 +
                                      (c0 + wb * 16 + lr)) * 8);
  __syncthreads();   // A-tile ready

  // preload ks=0 A-fragments from LDS
  bf16x8 axc[4];
#pragma unroll
  for (int rb = 0; rb < 4; ++rb) {
    int lrow = rb * 16 + lr;
    axc[rb] = *(const bf16x8*)(lds + lrow * 512 +
                               ((0 * 64 + lg * 16) ^ ((lrow & 7) << 4)));
  }

  // ---- phase A: depth-2 pipelined ----
  f32x4 acc[4][4] = {};
#pragma unroll
  for (int ks = 0; ks < 8; ++ks) {
    bf16x8 wfn[4], axn[4];
    if (ks < 7) {
#pragma unroll
      for (int wb = 0; wb < 4; ++wb)
        wfn[wb] = *(const bf16x8*)(w1f + ((size_t)((ks + 1) * 4 + lg) * 256 +
                                          (c0 + wb * 16 + lr)) * 8);
#pragma unroll
      for (int rb = 0; rb < 4; ++rb) {
        int lrow = rb * 16 + lr;
        axn[rb] = *(const bf16x8*)(lds + lrow * 512 +
                                   (((ks + 1) * 64 + lg * 16) ^ ((lrow & 7) << 4)));
      }
    }
#pragma unroll
    for (int wb = 0; wb < 4; ++wb)
#pragma unroll
      for (int rb = 0; rb < 4; ++rb)
        acc[wb][rb] = __builtin_amdgcn_mfma_f32_16x16x32_bf16(
            wfc[wb], axc[rb], acc[wb][rb], 0, 0, 0);
    if (ks < 7) {
#pragma unroll
      for (int i = 0; i < 4; ++i) { wfc[i] = wfn[i]; axc[i] = axn[i]; }
    }
  }

  __syncthreads();   // all A reads done before h overwrites

  // ---- epilogue A: h = relu(acc+b1) -> packed bf16x4 ----
  // D layout: lane&15 = x-row (within rb), (lane>>4)*4+i = w-col (within wb).
#pragma unroll
  for (int wb = 0; wb < 4; ++wb) {
    float4 b4 = *(const float4*)(b1 + c0 + wb * 16 + lg * 4);
#pragma unroll
    for (int rb = 0; rb < 4; ++rb) {
      int xrow = rb * 16 + lr;
      bf16x4 o;
      o[0] = (bf16_t)fmaxf(acc[wb][rb][0] + b4.x, 0.f);
      o[1] = (bf16_t)fmaxf(acc[wb][rb][1] + b4.y, 0.f);
      o[2] = (bf16_t)fmaxf(acc[wb][rb][2] + b4.z, 0.f);
      o[3] = (bf16_t)fmaxf(acc[wb][rb][3] + b4.w, 0.f);
      *(bf16x4*)(lds + xrow * 512 +
                 ((c0 * 2 + wb * 32 + lg * 8) ^ ((xrow & 7) << 4))) = o;
    }
  }
  __syncthreads();

  // ---- phase B: depth-2 pipelined; wave owns rows wv*16..wv*16+15 ----
  const int arow = wv * 16 + lr;
  bf16x8 hfc = *(const bf16x8*)(lds + arow * 512 +
                                ((0 * 64 + lg * 16) ^ ((arow & 7) << 4)));
  bf16x8 w2c[5];
#pragma unroll
  for (int wb = 0; wb < 5; ++wb)
    w2c[wb] = *(const bf16x8*)(w2f + ((size_t)(0 * 4 + lg) * 80 +
                                      (wb * 16 + lr)) * 8);

  f32x4 acc2[5] = {};
#pragma unroll
  for (int ks = 0; ks < 8; ++ks) {
    bf16x8 hfn, w2n[5];
    if (ks < 7) {
      hfn = *(const bf16x8*)(lds + arow * 512 +
                             (((ks + 1) * 64 + lg * 16) ^ ((arow & 7) << 4)));
#pragma unroll
      for (int wb = 0; wb < 5; ++wb)
        w2n[wb] = *(const bf16x8*)(w2f + ((size_t)((ks + 1) * 4 + lg) * 80 +
                                          (wb * 16 + lr)) * 8);
    }
#pragma unroll
    for (int wb = 0; wb < 5; ++wb)
      acc2[wb] = __builtin_amdgcn_mfma_f32_16x16x32_bf16(
          w2c[wb], hfc, acc2[wb], 0, 0, 0);
    if (ks < 7) {
      hfc = hfn;
#pragma unroll
      for (int i = 0; i < 5; ++i) w2c[i] = w2n[i];
    }
  }

  // ---- stores: lane holds 4 consecutive out-cols for ONE row ----
  const int r = m0 + wv * 16 + lr;
  if (r < N) {
#pragma unroll
    for (int wb = 0; wb < 5; ++wb) {
      int col0 = wb * 16 + lg * 4;
      f32x4 v = acc2[wb];
      if (col0 < 40) {
        float4 b4 = *(const float4*)(b2v + col0);
        v[0] += b4.x; v[1] += b4.y; v[2] += b4.z; v[3] += b4.w;
        *(f32x4*)(out + (size_t)r * 40 + col0) = v;
      } else {
        bf16x4 o;
        o[0] = (bf16_t)v[0]; o[1] = (bf16_t)v[1];
        o[2] = (bf16_t)v[2]; o[3] = (bf16_t)v[3];
        *(bf16x4*)(p + (size_t)r * 40 + (col0 - 40)) = o;
      }
    }
  }
}

// ---------------- layer-2 mean: out += mean2(p); 4-way unrolled bf16 gather ---
__global__ void k_agg2fin(const bf16_t* __restrict__ p, const int* __restrict__ rowptr,
                          const int* __restrict__ csr, float* __restrict__ out, int N) {
  int t = blockIdx.x * 256 + threadIdx.x;
  int node = t / 10, l = t - node * 10;
  if (node >= N) return;
  int beg = rowptr[node], end = rowptr[node + 1];
  float a0 = 0.f, a1 = 0.f, a2 = 0.f, a3 = 0.f;
  int e = beg;
  for (; e + 4 <= end; e += 4) {
    int s0 = csr[e], s1 = csr[e + 1], s2 = csr[e + 2], s3 = csr[e + 3];
    bf16x4 v0 = *(const bf16x4*)(p + (size_t)s0 * 40 + l * 4);
    bf16x4 v1 = *(const bf16x4*)(p + (size_t)s1 * 40 + l * 4);
    bf16x4 v2 = *(const bf16x4*)(p + (size_t)s2 * 40 + l * 4);
    bf16x4 v3 = *(const bf16x4*)(p + (size_t)s3 * 40 + l * 4);
    a0 += (float)v0[0] + (float)v1[0] + (float)v2[0] + (float)v3[0];
    a1 += (float)v0[1] + (float)v1[1] + (float)v2[1] + (float)v3[1];
    a2 += (float)v0[2] + (float)v1[2] + (float)v2[2] + (float)v3[2];
    a3 += (float)v0[3] + (float)v1[3] + (float)v2[3] + (float)v3[3];
  }
  for (; e < end; ++e) {
    int s = csr[e];
    bf16x4 v = *(const bf16x4*)(p + (size_t)s * 40 + l * 4);
    a0 += (float)v[0]; a1 += (float)v[1]; a2 += (float)v[2]; a3 += (float)v[3];
  }
  float rd = (end > beg) ? 1.0f / (float)(end - beg) : 0.0f;
  float* o = out + (size_t)node * 40 + l * 4;
  float4 cur = *(const float4*)o;
  cur.x += a0 * rd;
  cur.y += a1 * rd;
  cur.z += a2 * rd;
  cur.w += a3 * rd;
  *(float4*)o = cur;
}

extern "C" void kernel_launch(void* const* d_in, const int* in_sizes, int n_in,
                              void* d_out, int out_size, void* d_ws, size_t ws_size,
                              hipStream_t stream) {
  const float* x    = (const float*)d_in[0];
  const int*   src1 = (const int*)d_in[1];
  const int*   dst1 = (const int*)d_in[2];
  const int*   src2 = (const int*)d_in[3];
  const int*   dst2 = (const int*)d_in[4];
  const float* ws1  = (const float*)d_in[5];
  const float* wn1  = (const float*)d_in[6];
  const float* b1   = (const float*)d_in[7];
  const float* ws2  = (const float*)d_in[8];
  const float* wn2  = (const float*)d_in[9];
  const float* b2   = (const float*)d_in[10];
  float*       out  = (float*)d_out;

  const int N = in_sizes[0] / D_IN;
  const int E = in_sizes[1];
  if (ws_size < WS_NEEDED) return;

  char*     ws   = (char*)d_ws;
  int*      hg1  = (int*)(ws + HG1_OFF);
  int*      hg2  = (int*)(ws + HG2_OFF);
  int*      bs1  = (int*)(ws + BS1_OFF);
  int*      bs2  = (int*)(ws + BS2_OFF);
  int*      rp1  = (int*)(ws + RP1_OFF);
  int*      rp2  = (int*)(ws + RP2_OFF);
  unsigned* bkt1 = (unsigned*)(ws + BKT1_OFF);
  unsigned* bkt2 = (unsigned*)(ws + BKT2_OFF);
  int*      csr1 = (int*)(ws + BKT1_OFF);     // aliases bkt1 (safe: see k_bcsr)
  int*      csr2 = (int*)(ws + BKT2_OFF);     // aliases bkt2
  bf16_t*   xcat = (bf16_t*)(ws + XCAT_OFF);
  bf16_t*   p    = (bf16_t*)(ws + P_OFF);
  bf16_t*   w1f  = (bf16_t*)(ws + W1F_OFF);
  bf16_t*   w2f  = (bf16_t*)(ws + W2F_OFF);

  const int nbkt  = (N + 255) >> 8;            // 391
  const int chunk = (E + NBLK - 1) / NBLK;     // 4688
  const int nsc   = nbkt * NBLK;               // 50048
  const int nscb  = (nsc + 255) / 256;         // 196 (<=256)
  const int nconvx = (N * 16 + 255) / 256;     // 6250
  const int ntiles = (N + 63) / 64;            // 1563

  k_prep<<<nconvx + 32 + 2 * NBLK, 256, 0, stream>>>(
      x, xcat, ws1, wn1, ws2, wn2, w1f, w2f, dst1, dst2, hg1, hg2,
      N, E, chunk, nbkt, nconvx);

  k_scan_block<<<dim3(nscb, 2), 256, 0, stream>>>(hg1, hg2, bs1, bs2, nsc);
  k_scan_addsums<<<dim3(nscb, 2), 256, 0, stream>>>(hg1, hg2, bs1, bs2, nsc, nscb);
  k_scat<<<dim3(NBLK, 2), 256, 0, stream>>>(src1, dst1, src2, dst2, hg1, hg2,
                                            bkt1, bkt2, E, chunk, nbkt);
  k_bcsr<<<dim3(nbkt, 2), 256, 0, stream>>>(hg1, hg2, bkt1, bkt2, csr1, csr2,
                                            rp1, rp2, E, N, nbkt);

  k_agg1<<<(N * 16 + 255) / 256, 256, 0, stream>>>(xcat, rp1, csr1, N);
  k_fused<<<ntiles, 256, 0, stream>>>(xcat, w1f, b1, w2f, b2, out, p, N);
  k_agg2fin<<<(N * 10 + 255) / 256, 256, 0, stream>>>(p, rp2, csr2, out, N);
}